// Round 12
// baseline (2067.069 us; speedup 1.0000x reference)
//
#include <hip/hip_runtime.h>
#include <math.h>
#include <float.h>

// Problem constants: B=4, N=3136, C=64, C2=128, H=W=56, stride2 -> 28x28,
// Ns = ceil(N*0.25) = 784, k = 5.  Inputs are float32/int32 per reference.
#define Bq   4
#define Nq   3136
#define Cq   64
#define C2q  128
#define Hq   56
#define Wq   56
#define HOq  28
#define WOq  28
#define NSq  784
#define KNN  5
#define BNq  (Bq*Nq)

#define T64   64             // i/j tile for distance kernels
#define KC    32             // K chunk
#define NIT64 (Nq/T64)       // 49 i-tiles (exact)
#define NT_C  ((NSq+T64-1)/T64) // 13 center tiles (last partial)
#define NSPL  4              // j-range splits (grid 784)
#define LDP   34             // LDS row stride (even -> 16B-aligned double2)

__device__ __constant__ int c_spl[NSPL + 1] = {0, 13, 25, 37, 49};

typedef unsigned int   u32;
typedef unsigned long long u64;

static __device__ __forceinline__ void atomicMaxPosD(double* p, double v) {
    atomicMax((u64*)p, (u64)__double_as_longlong(v));
}
static __device__ __forceinline__ int clampTok(int t) {
    return min(max(t, 0), Nq - 1);
}

// sorted-ascending insert into 5-list (static indices after unroll)
static __device__ __forceinline__ void ins5(double* a, double v) {
    if (v < a[KNN - 1]) {
        a[KNN - 1] = v;
        #pragma unroll
        for (int m = KNN - 1; m > 0; m--)
            if (a[m] < a[m - 1]) { double t = a[m]; a[m] = a[m - 1]; a[m - 1] = t; }
    }
}
// compare-exchange (branch-free, static)
static __device__ __forceinline__ void cex(double& a, double& b) {
    double lo = fmin(a, b), hi = fmax(a, b); a = lo; b = hi;
}
// merge two ascending 5-lists, keep 5 smallest ascending.
// STATIC INDICES ONLY (SROA -> VGPRs). Bitonic halver + bubble network.
static __device__ __forceinline__ void merge5(double* a, const double* p) {
    double t0 = fmin(a[0], p[4]);
    double t1 = fmin(a[1], p[3]);
    double t2 = fmin(a[2], p[2]);
    double t3 = fmin(a[3], p[1]);
    double t4 = fmin(a[4], p[0]);
    cex(t0, t1); cex(t1, t2); cex(t2, t3); cex(t3, t4);
    cex(t0, t1); cex(t1, t2); cex(t2, t3);
    cex(t0, t1); cex(t1, t2);
    cex(t0, t1);
    a[0] = t0; a[1] = t1; a[2] = t2; a[3] = t3; a[4] = t4;
}

// ---- jax threefry2x32 noise: uniform(key(42), (4,3136)) -------------------
static __device__ __forceinline__ u32 rotl32(u32 x, int d) { return (x << d) | (x >> (32 - d)); }
static __device__ __forceinline__ float tf_uniform(int t) {
    const u32 k0 = 0u, k1 = 42u;
    const u32 ks2 = k0 ^ k1 ^ 0x1BD11BDAu;
    u32 ks[3] = { k0, k1, ks2 };
    bool lo = (t < 6272);
    u32 cx0 = lo ? (u32)t : (u32)(t - 6272);
    u32 cx1 = lo ? (u32)(t + 6272) : (u32)t;
    u32 x0 = cx0 + ks[0];
    u32 x1 = cx1 + ks[1];
    const int R0[4] = {13, 15, 26, 6};
    const int R1[4] = {17, 29, 16, 24};
    #pragma unroll
    for (int i = 0; i < 5; i++) {
        const int* rot = (i % 2 == 0) ? R0 : R1;
        #pragma unroll
        for (int r = 0; r < 4; r++) { x0 += x1; x1 = rotl32(x1, rot[r]); x1 ^= x0; }
        x0 += ks[(i + 1) % 3];
        x1 += ks[(i + 2) % 3] + (u32)(i + 1);
    }
    u32 bits = lo ? x0 : x1;
    u32 fb = (bits >> 9) | 0x3f800000u;
    float f; __builtin_memcpy(&f, &fb, 4);
    return f - 1.0f;
}

// ---- grid index: clip(loc,-1,1)*0.5+0.5 -> round-half-even ----------------
static __device__ __forceinline__ int gridIndex(float lx, float ly, int Wd, int Hd) {
    double x = fmin(fmax((double)lx, -1.0), 1.0) * 0.5 + 0.5;
    double y = fmin(fmax((double)ly, -1.0), 1.0) * 0.5 + 0.5;
    int ix = (int)rint(x * (double)(Wd - 1)); ix = min(max(ix, 0), Wd - 1);
    int iy = (int)rint(y * (double)(Hd - 1)); iy = min(max(iy, 0), Hd - 1);
    return iy * Wd + ix;
}

// ---------------------------------------------------------------------------
__global__ void ctm_fallback(float* out, int n) {
    int t = blockIdx.x * blockDim.x + threadIdx.x;
    if (t < n) out[t] = 0.0f;
}

__global__ void ctm_prep(const float* __restrict__ loc, const int* __restrict__ idx_agg,
                         const float* __restrict__ aggw,
                         int* cell56, int* cell28, int* cnt56, double* allwtok) {
    int t = blockIdx.x * blockDim.x + threadIdx.x;
    if (t >= BNq) return;
    int b = t / Nq;
    float lx = loc[2 * t], ly = loc[2 * t + 1];
    int c56 = gridIndex(lx, ly, Wq, Hq);
    int c28 = gridIndex(lx, ly, WOq, HOq);
    cell56[t] = c56; cell28[t] = c28;
    atomicAdd(&cnt56[b * (Hq * Wq) + c56], 1);
    int tok = clampTok(idx_agg[t]);
    atomicAdd(&allwtok[b * Nq + tok], (double)aggw[t]);
}

__global__ void ctm_t2m(const float* __restrict__ x, const int* __restrict__ idx_agg,
                        const int* __restrict__ cell56, const int* __restrict__ cnt56,
                        double* xmap56) {
    int t = blockIdx.x * blockDim.x + threadIdx.x;
    if (t >= BNq) return;
    int b = t / Nq;
    int cell = cell56[t];
    double v = 1.0 / ((double)cnt56[b * (Hq * Wq) + cell] + 1e-6);
    const float* xr = x + (size_t)(b * Nq + clampTok(idx_agg[t])) * Cq;
    double* base = xmap56 + (size_t)b * Cq * (Hq * Wq) + cell;
    #pragma unroll 8
    for (int c = 0; c < Cq; c++)
        atomicAdd(base + (size_t)c * (Hq * Wq), (double)xr[c] * v);
}

__global__ void ctm_conv(const double* __restrict__ xmap56, const float* __restrict__ w,
                         const float* __restrict__ bias, double* xmap28) {
    int t = blockIdx.x * blockDim.x + threadIdx.x;
    if (t >= Bq * C2q * HOq * WOq) return;
    int ox = t % WOq, oy = (t / WOq) % HOq, co = (t / (HOq * WOq)) % C2q, b = t / (C2q * HOq * WOq);
    double acc = (double)bias[co];
    const float* wr = w + (size_t)co * Cq * 9;
    const double* xb = xmap56 + (size_t)b * Cq * (Hq * Wq);
    #pragma unroll 4
    for (int ci = 0; ci < Cq; ci++) {
        for (int ky = 0; ky < 3; ky++) {
            int iy = 2 * oy + ky - 1; if (iy < 0 || iy >= Hq) continue;
            for (int kx = 0; kx < 3; kx++) {
                int ix = 2 * ox + kx - 1; if (ix < 0 || ix >= Wq) continue;
                acc += xb[(size_t)ci * (Hq * Wq) + iy * Wq + ix] * (double)wr[ci * 9 + ky * 3 + kx];
            }
        }
    }
    xmap28[t] = acc;
}

__global__ void ctm_m2t(const double* __restrict__ xmap28, const float* __restrict__ aggw,
                        const int* __restrict__ idx_agg, const int* __restrict__ cell28,
                        const double* __restrict__ allwtok, double* xt) {
    int t = blockIdx.x * blockDim.x + threadIdx.x;
    if (t >= BNq) return;
    int b = t / Nq;
    int tok = clampTok(idx_agg[t]);
    double v = (double)aggw[t] / (allwtok[b * Nq + tok] + 1e-6);
    int cell = cell28[t];
    const double* f = xmap28 + (size_t)b * C2q * (HOq * WOq) + cell;
    double* dst = xt + (size_t)(b * Nq + tok) * C2q;
    #pragma unroll 8
    for (int c = 0; c < C2q; c++)
        atomicAdd(&dst[c], f[(size_t)c * (HOq * WOq)] * v);
}

__global__ __launch_bounds__(C2q)
void ctm_finalize(double* xt, const float* __restrict__ x, const float* __restrict__ skipw,
                  const float* __restrict__ lng, const float* __restrict__ lnb,
                  const float* __restrict__ confw, const float* __restrict__ confb,
                  double* x2o, double* weightv) {
    int bn = blockIdx.x; int c = threadIdx.x;
    double* row = xt + (size_t)bn * C2q;
    const float* xr = x + (size_t)bn * Cq;
    double acc = row[c];
    const float* sw = skipw + c * Cq;
    #pragma unroll 16
    for (int k = 0; k < Cq; k++) acc += (double)xr[k] * (double)sw[k];
    __shared__ double red[C2q];
    __shared__ double stat[2];
    red[c] = acc; __syncthreads();
    for (int off = C2q / 2; off > 0; off >>= 1) { if (c < off) red[c] += red[c + off]; __syncthreads(); }
    if (c == 0) stat[0] = red[0] * (1.0 / C2q);
    __syncthreads();
    double mu = stat[0];
    double d = acc - mu;
    red[c] = d * d; __syncthreads();
    for (int off = C2q / 2; off > 0; off >>= 1) { if (c < off) red[c] += red[c + off]; __syncthreads(); }
    if (c == 0) stat[1] = red[0] * (1.0 / C2q);
    __syncthreads();
    double var = stat[1];
    double v = d / sqrt(var + 1e-5) * (double)lng[c] + (double)lnb[c];
    row[c] = v;
    red[c] = v * v; __syncthreads();
    for (int off = C2q / 2; off > 0; off >>= 1) { if (c < off) red[c] += red[c + off]; __syncthreads(); }
    if (c == 0) x2o[bn] = red[0];
    __syncthreads();
    red[c] = v * (double)confw[c]; __syncthreads();
    for (int off = C2q / 2; off > 0; off >>= 1) { if (c < off) red[c] += red[c + off]; __syncthreads(); }
    if (c == 0) weightv[bn] = exp(red[0] + (double)confb[0]);
}

// ---------------------------------------------------------------------------
// Distance kernels v2.4: as R11 (64x64 tiles, 4x4 micro-tile, double2 LDS
// reads, stride-34 rows, NSPL=4 j-split) but __launch_bounds__(256, 2):
// measured across rounds -- bare(256): VGPR 64 + 338 MB spill; (256,4):
// VGPR 64 + 240 MB spill; (256,2): VGPR 84, NO spill. The backend spills
// down to 64 regs chasing high wave targets; min=2 lets it take the ~84 the
// micro-tile needs, and at 84 VGPR + 35 KB LDS the HW still hosts ~4
// blocks/CU at runtime. Bit-identical arithmetic (c ascending per pair).
// ---------------------------------------------------------------------------

// pass1: per row i -> 5 smallest d2 + row max d2 (partial per j-split)
__global__ __launch_bounds__(256, 2)
void ctm_pass1(const double* __restrict__ xt, const double* __restrict__ x2,
               double* pbest, double* pmax) {
    __shared__ double sA[T64][LDP];
    __shared__ double sB[T64][LDP];
    __shared__ double sx2j[T64];
    int blk = blockIdx.x;
    int s  = blk & (NSPL - 1);
    int it = (blk >> 2) % NIT64;
    int b  = blk / (NSPL * NIT64);
    int tid = threadIdx.x, tx = tid & 15, ty = tid >> 4;
    const double* xtb = xt + (size_t)b * Nq * C2q;
    const double* x2b = x2 + (size_t)b * Nq;
    int i0 = it * T64;
    double x2i[4];
    #pragma unroll
    for (int r = 0; r < 4; r++) x2i[r] = x2b[i0 + ty + 16 * r];
    double best[4][KNN]; double mx[4];
    #pragma unroll
    for (int r = 0; r < 4; r++) {
        mx[r] = -DBL_MAX;
        #pragma unroll
        for (int k = 0; k < KNN; k++) best[r][k] = DBL_MAX;
    }
    int jt_beg = c_spl[s], jt_end = c_spl[s + 1];
    for (int jt = jt_beg; jt < jt_end; jt++) {
        int j0 = jt * T64;
        double acc[4][4];
        #pragma unroll
        for (int r = 0; r < 4; r++)
            #pragma unroll
            for (int q = 0; q < 4; q++) acc[r][q] = 0.0;
        for (int kc = 0; kc < 4; kc++) {
            __syncthreads();
            for (int idx = tid; idx < T64 * KC; idx += 256) {
                int r = idx >> 5, c = idx & 31;
                sA[r][c] = xtb[(size_t)(i0 + r) * C2q + kc * KC + c];
                sB[r][c] = xtb[(size_t)(j0 + r) * C2q + kc * KC + c];
            }
            if (kc == 0 && tid < T64) sx2j[tid] = x2b[j0 + tid];
            __syncthreads();
            #pragma unroll 4
            for (int cc = 0; cc < KC; cc += 2) {
                double2 xi[4], xj[4];
                #pragma unroll
                for (int r = 0; r < 4; r++) xi[r] = *(const double2*)&sA[ty + 16 * r][cc];
                #pragma unroll
                for (int q = 0; q < 4; q++) xj[q] = *(const double2*)&sB[tx + 16 * q][cc];
                #pragma unroll
                for (int r = 0; r < 4; r++)
                    #pragma unroll
                    for (int q = 0; q < 4; q++) acc[r][q] += xi[r].x * xj[q].x;
                #pragma unroll
                for (int r = 0; r < 4; r++)
                    #pragma unroll
                    for (int q = 0; q < 4; q++) acc[r][q] += xi[r].y * xj[q].y;
            }
        }
        #pragma unroll
        for (int r = 0; r < 4; r++)
            #pragma unroll
            for (int q = 0; q < 4; q++) {
                double d2 = x2i[r] + sx2j[tx + 16 * q] - 2.0 * acc[r][q];
                mx[r] = fmax(mx[r], d2);
                ins5(best[r], d2);
            }
    }
    for (int m = 1; m <= 8; m <<= 1) {
        #pragma unroll
        for (int r = 0; r < 4; r++) {
            double p[KNN];
            #pragma unroll
            for (int k = 0; k < KNN; k++) p[k] = __shfl_xor(best[r][k], m);
            mx[r] = fmax(mx[r], __shfl_xor(mx[r], m));
            merge5(best[r], p);
        }
    }
    if (tx == 0) {
        #pragma unroll
        for (int r = 0; r < 4; r++) {
            int gi = b * Nq + i0 + ty + 16 * r;
            size_t base = ((size_t)s * BNq + gi) * KNN;
            #pragma unroll
            for (int k = 0; k < KNN; k++) pbest[base + k] = best[r][k];
            pmax[(size_t)s * BNq + gi] = mx[r];
        }
    }
}

// merge pass1 partials -> density + rowmax2
__global__ void ctm_merge1(const double* __restrict__ pbest, const double* __restrict__ pmax,
                           double* density, double* rowmax2) {
    int t = blockIdx.x * blockDim.x + threadIdx.x;
    if (t >= BNq) return;
    double a[KNN];
    #pragma unroll
    for (int k = 0; k < KNN; k++) a[k] = pbest[(size_t)t * KNN + k];
    double mxv = pmax[t];
    #pragma unroll
    for (int s = 1; s < NSPL; s++) {
        double p[KNN];
        #pragma unroll
        for (int k = 0; k < KNN; k++) p[k] = pbest[((size_t)s * BNq + t) * KNN + k];
        merge5(a, p);
        mxv = fmax(mxv, pmax[(size_t)s * BNq + t]);
    }
    double sum = 0.0;
    #pragma unroll
    for (int k = 0; k < KNN; k++) sum += fmax(a[k], 0.0);
    density[t] = exp(-sum / (double)(C2q * KNN)) + (double)(tf_uniform(t) * 1e-6f);
    rowmax2[t] = mxv;
}

__global__ __launch_bounds__(256)
void ctm_rowmax(const double* __restrict__ rowmax2, double* maxd2) {
    int b = blockIdx.x, tid = threadIdx.x;
    double m = -DBL_MAX;
    for (int i = tid; i < Nq; i += 256) m = fmax(m, rowmax2[b * Nq + i]);
    __shared__ double sm[256];
    sm[tid] = m; __syncthreads();
    for (int off = 128; off > 0; off >>= 1) { if (tid < off) sm[tid] = fmax(sm[tid], sm[tid + off]); __syncthreads(); }
    if (tid == 0) maxd2[b] = sm[0];
}

// pass2: min d2 over higher-density j (partial per j-split)
__global__ __launch_bounds__(256, 2)
void ctm_pass2(const double* __restrict__ xt, const double* __restrict__ x2,
               const double* __restrict__ density, double* pmin) {
    __shared__ double sA[T64][LDP];
    __shared__ double sB[T64][LDP];
    __shared__ double sx2j[T64];
    __shared__ double sdj[T64];
    int blk = blockIdx.x;
    int s  = blk & (NSPL - 1);
    int it = (blk >> 2) % NIT64;
    int b  = blk / (NSPL * NIT64);
    int tid = threadIdx.x, tx = tid & 15, ty = tid >> 4;
    const double* xtb = xt + (size_t)b * Nq * C2q;
    const double* x2b = x2 + (size_t)b * Nq;
    const double* db  = density + (size_t)b * Nq;
    int i0 = it * T64;
    double x2i[4], di[4], mn[4];
    #pragma unroll
    for (int r = 0; r < 4; r++) {
        x2i[r] = x2b[i0 + ty + 16 * r];
        di[r]  = db[i0 + ty + 16 * r];
        mn[r]  = DBL_MAX;
    }
    int jt_beg = c_spl[s], jt_end = c_spl[s + 1];
    for (int jt = jt_beg; jt < jt_end; jt++) {
        int j0 = jt * T64;
        double acc[4][4];
        #pragma unroll
        for (int r = 0; r < 4; r++)
            #pragma unroll
            for (int q = 0; q < 4; q++) acc[r][q] = 0.0;
        for (int kc = 0; kc < 4; kc++) {
            __syncthreads();
            for (int idx = tid; idx < T64 * KC; idx += 256) {
                int r = idx >> 5, c = idx & 31;
                sA[r][c] = xtb[(size_t)(i0 + r) * C2q + kc * KC + c];
                sB[r][c] = xtb[(size_t)(j0 + r) * C2q + kc * KC + c];
            }
            if (kc == 0 && tid < T64) { sx2j[tid] = x2b[j0 + tid]; sdj[tid] = db[j0 + tid]; }
            __syncthreads();
            #pragma unroll 4
            for (int cc = 0; cc < KC; cc += 2) {
                double2 xi[4], xj[4];
                #pragma unroll
                for (int r = 0; r < 4; r++) xi[r] = *(const double2*)&sA[ty + 16 * r][cc];
                #pragma unroll
                for (int q = 0; q < 4; q++) xj[q] = *(const double2*)&sB[tx + 16 * q][cc];
                #pragma unroll
                for (int r = 0; r < 4; r++)
                    #pragma unroll
                    for (int q = 0; q < 4; q++) acc[r][q] += xi[r].x * xj[q].x;
                #pragma unroll
                for (int r = 0; r < 4; r++)
                    #pragma unroll
                    for (int q = 0; q < 4; q++) acc[r][q] += xi[r].y * xj[q].y;
            }
        }
        #pragma unroll
        for (int r = 0; r < 4; r++)
            #pragma unroll
            for (int q = 0; q < 4; q++) {
                double d2 = x2i[r] + sx2j[tx + 16 * q] - 2.0 * acc[r][q];
                if (sdj[tx + 16 * q] > di[r]) mn[r] = fmin(mn[r], d2);
            }
    }
    for (int m = 1; m <= 8; m <<= 1) {
        #pragma unroll
        for (int r = 0; r < 4; r++) mn[r] = fmin(mn[r], __shfl_xor(mn[r], m));
    }
    if (tx == 0) {
        #pragma unroll
        for (int r = 0; r < 4; r++) {
            int gi = b * Nq + i0 + ty + 16 * r;
            pmin[(size_t)s * BNq + gi] = mn[r];
        }
    }
}

// merge pass2 partials -> score
__global__ void ctm_merge2(const double* __restrict__ pmin, const double* __restrict__ maxd2,
                           const double* __restrict__ density, double* score) {
    int t = blockIdx.x * blockDim.x + threadIdx.x;
    if (t >= BNq) return;
    int b = t / Nq;
    double m = pmin[t];
    #pragma unroll
    for (int s = 1; s < NSPL; s++) m = fmin(m, pmin[(size_t)s * BNq + t]);
    double mm = fmin(maxd2[b], m);
    score[t] = sqrt(fmax(mm, 0.0)) / sqrt((double)C2q) * density[t];
}

// top-784 with jax.lax.top_k semantics: total order (score desc, idx asc).
__global__ __launch_bounds__(1024)
void ctm_sort(const double* __restrict__ score, int* index_down) {
    __shared__ double s[4096];
    __shared__ int   si[4096];
    int b = blockIdx.x, tid = threadIdx.x;
    for (int i = tid; i < 4096; i += 1024) {
        if (i < Nq) {
            double v = score[b * Nq + i];
            s[i] = isnan(v) ? -DBL_MAX : v;
            si[i] = i;
        } else { s[i] = -DBL_MAX; si[i] = 0x7fffffff; }
    }
    __syncthreads();
    for (int k = 2; k <= 4096; k <<= 1) {
        for (int j = k >> 1; j > 0; j >>= 1) {
            for (int i = tid; i < 4096; i += 1024) {
                int ixj = i ^ j;
                if (ixj > i) {
                    double s1 = s[i], s2 = s[ixj];
                    int i1 = si[i], i2 = si[ixj];
                    bool before_ij = (s1 > s2) || (s1 == s2 && i1 < i2);
                    bool before_ji = (s2 > s1) || (s2 == s1 && i2 < i1);
                    bool doswap = ((i & k) == 0) ? before_ji : before_ij;
                    if (doswap) { s[i] = s2; s[ixj] = s1; si[i] = i2; si[ixj] = i1; }
                }
            }
            __syncthreads();
        }
    }
    for (int t = tid; t < NSq; t += 1024) {
        int v = si[t];
        index_down[b * NSq + t] = ((unsigned)v < (unsigned)Nq) ? v : 0;
    }
}

// assign: argmin over 784 centers, tie-break smallest sc (lexicographic d,sc)
__global__ __launch_bounds__(256, 2)
void ctm_assign(const double* __restrict__ xt, const double* __restrict__ x2,
                const int* __restrict__ index_down, int* idx_cluster) {
    __shared__ double sA[T64][LDP];
    __shared__ double sB[T64][LDP];
    __shared__ double sx2c[T64];
    __shared__ int    sidx[T64];
    int blk = blockIdx.x;
    int it = blk % NIT64;
    int b  = blk / NIT64;
    int tid = threadIdx.x, tx = tid & 15, ty = tid >> 4;
    const double* xtb = xt + (size_t)b * Nq * C2q;
    const double* x2b = x2 + (size_t)b * Nq;
    int i0 = it * T64;
    double x2i[4], bd[4];
    int bs[4];
    #pragma unroll
    for (int r = 0; r < 4; r++) { x2i[r] = x2b[i0 + ty + 16 * r]; bd[r] = DBL_MAX; bs[r] = NSq - 1; }
    for (int jt = 0; jt < NT_C; jt++) {
        int j0 = jt * T64;
        __syncthreads();
        if (tid < T64) {
            int j = index_down[b * NSq + min(j0 + tid, NSq - 1)];
            sidx[tid] = j;
            sx2c[tid] = x2b[j];
        }
        __syncthreads();
        double acc[4][4];
        #pragma unroll
        for (int r = 0; r < 4; r++)
            #pragma unroll
            for (int q = 0; q < 4; q++) acc[r][q] = 0.0;
        for (int kc = 0; kc < 4; kc++) {
            if (kc) __syncthreads();
            for (int idx = tid; idx < T64 * KC; idx += 256) {
                int r = idx >> 5, c = idx & 31;
                sA[r][c] = xtb[(size_t)(i0 + r) * C2q + kc * KC + c];
                sB[r][c] = xtb[(size_t)sidx[r] * C2q + kc * KC + c];
            }
            __syncthreads();
            #pragma unroll 4
            for (int cc = 0; cc < KC; cc += 2) {
                double2 xi[4], xj[4];
                #pragma unroll
                for (int r = 0; r < 4; r++) xi[r] = *(const double2*)&sA[ty + 16 * r][cc];
                #pragma unroll
                for (int q = 0; q < 4; q++) xj[q] = *(const double2*)&sB[tx + 16 * q][cc];
                #pragma unroll
                for (int r = 0; r < 4; r++)
                    #pragma unroll
                    for (int q = 0; q < 4; q++) acc[r][q] += xi[r].x * xj[q].x;
                #pragma unroll
                for (int r = 0; r < 4; r++)
                    #pragma unroll
                    for (int q = 0; q < 4; q++) acc[r][q] += xi[r].y * xj[q].y;
            }
        }
        #pragma unroll
        for (int r = 0; r < 4; r++)
            #pragma unroll
            for (int q = 0; q < 4; q++) {
                int sc = j0 + tx + 16 * q;
                double d = fmax(x2i[r] + sx2c[tx + 16 * q] - 2.0 * acc[r][q], 0.0);
                if (sc < NSq && (d < bd[r] || (d == bd[r] && sc < bs[r]))) { bd[r] = d; bs[r] = sc; }
            }
    }
    for (int m = 1; m <= 8; m <<= 1) {
        #pragma unroll
        for (int r = 0; r < 4; r++) {
            double pd = __shfl_xor(bd[r], m);
            int    ps = __shfl_xor(bs[r], m);
            if (pd < bd[r] || (pd == bd[r] && ps < bs[r])) { bd[r] = pd; bs[r] = ps; }
        }
    }
    if (tx == 0) {
        #pragma unroll
        for (int r = 0; r < 4; r++) idx_cluster[b * Nq + i0 + ty + 16 * r] = bs[r];
    }
}

__global__ void ctm_override(const int* __restrict__ index_down, int* idx_cluster) {
    int t = blockIdx.x * blockDim.x + threadIdx.x;
    if (t >= Bq * NSq) return;
    int b = t / NSq, sc = t - b * NSq;
    int j = index_down[t];
    if ((unsigned)j < (unsigned)Nq) idx_cluster[b * Nq + j] = sc;
}

__global__ void ctm_zeromerged(double* xmerged) {
    int t = blockIdx.x * blockDim.x + threadIdx.x;
    if (t < Bq * NSq * C2q) xmerged[t] = 0.0;
}

__global__ void ctm_merge_w(const int* __restrict__ idx_cluster, const double* __restrict__ weightv,
                            double* allwc) {
    int t = blockIdx.x * blockDim.x + threadIdx.x;
    if (t >= BNq) return;
    int b = t / Nq;
    int sc = min(max(idx_cluster[t], 0), NSq - 1);
    atomicAdd(&allwc[b * NSq + sc], weightv[t]);
}

__global__ void ctm_merge_x(const int* __restrict__ idx_cluster, const double* __restrict__ weightv,
                            const double* __restrict__ allwc, const double* __restrict__ xt,
                            double* nw, double* xmerged) {
    int t = blockIdx.x * blockDim.x + threadIdx.x;
    if (t >= BNq) return;
    int b = t / Nq;
    int sc = min(max(idx_cluster[t], 0), NSq - 1);
    double nv = weightv[t] / (allwc[b * NSq + sc] + 1e-6);
    nw[t] = nv;
    const double* xrow = xt + (size_t)t * C2q;
    double* dst = xmerged + (size_t)(b * NSq + sc) * C2q;
    #pragma unroll 8
    for (int c = 0; c < C2q; c++) atomicAdd(&dst[c], xrow[c] * nv);
}

__global__ void ctm_out0(const double* __restrict__ xmerged, float* out) {
    int t = blockIdx.x * blockDim.x + threadIdx.x;
    if (t >= Bq * NSq * C2q) return;
    out[t] = (float)xmerged[t];
}

__global__ void ctm_out12(const int* __restrict__ idx_agg, const int* __restrict__ idx_cluster,
                          const double* __restrict__ nw, const float* __restrict__ aggw,
                          float* out1, double* awd, double* maxawd) {
    int t = blockIdx.x * blockDim.x + threadIdx.x;
    if (t >= BNq) return;
    int b = t / Nq;
    int tok = clampTok(idx_agg[t]);
    int sc = idx_cluster[b * Nq + tok];
    out1[t] = (float)sc;
    double a = (double)aggw[t] * nw[b * Nq + tok];
    awd[t] = a;
    atomicMaxPosD(&maxawd[b], a);
}

__global__ void ctm_out2(const double* __restrict__ awd, const double* __restrict__ maxawd, float* out2) {
    int t = blockIdx.x * blockDim.x + threadIdx.x;
    if (t >= BNq) return;
    int b = t / Nq;
    out2[t] = (float)(awd[t] / maxawd[b]);
}

// ---------------------------------------------------------------------------
extern "C" void kernel_launch(void* const* d_in, const int* in_sizes, int n_in,
                              void* d_out, int out_size, void* d_ws, size_t ws_size,
                              hipStream_t stream) {
    const float* x     = (const float*)d_in[0];
    const float* loc   = (const float*)d_in[1];
    const int*   idxag = (const int*)  d_in[2];
    const float* aggw  = (const float*)d_in[3];
    const float* convw = (const float*)d_in[4];
    const float* convb = (const float*)d_in[5];
    const float* skipw = (const float*)d_in[6];
    const float* lng   = (const float*)d_in[7];
    const float* lnb   = (const float*)d_in[8];
    const float* confw = (const float*)d_in[9];
    const float* confb = (const float*)d_in[10];
    (void)in_sizes; (void)n_in;

    char* w = (char*)d_ws;
    size_t off = 0;
    auto alloc = [&](size_t bytes) -> void* {
        void* p = w + off; off = (off + bytes + 255) & ~(size_t)255; return p;
    };

    // ---- zero-initialized region (one memset) ----
    int*    cnt56   = (int*)   alloc((size_t)BNq * 4);
    double* allwtok = (double*)alloc((size_t)BNq * 8);
    double* xt      = (double*)alloc((size_t)BNq * C2q * 8);
    double* arena   = (double*)alloc((size_t)Bq * Cq * Hq * Wq * 8);
    double* allwc   = (double*)alloc((size_t)Bq * NSq * 8);
    double* maxawd  = (double*)alloc((size_t)Bq * 8);
    size_t zero_bytes = off;
    // ---- non-zero region ----
    int*    cell56   = (int*)   alloc((size_t)BNq * 4);
    int*    cell28   = (int*)   alloc((size_t)BNq * 4);
    double* xmap28   = (double*)alloc((size_t)Bq * C2q * HOq * WOq * 8);
    double* x2       = (double*)alloc((size_t)BNq * 8);
    double* density  = (double*)alloc((size_t)BNq * 8);
    double* rowmax2  = (double*)alloc((size_t)BNq * 8);
    double* maxd2    = (double*)alloc((size_t)Bq * 8);
    double* score    = (double*)alloc((size_t)BNq * 8);
    int*    indexdn  = (int*)   alloc((size_t)Bq * NSq * 4);
    int*    idxclu   = (int*)   alloc((size_t)BNq * 4);
    double* nw       = (double*)alloc((size_t)BNq * 8);
    double* weightv  = (double*)alloc((size_t)BNq * 8);
    double* awd      = (double*)alloc((size_t)BNq * 8);
    double* pbest    = (double*)alloc((size_t)NSPL * BNq * KNN * 8);
    double* pmax     = (double*)alloc((size_t)NSPL * BNq * 8);
    double* pmin     = (double*)alloc((size_t)NSPL * BNq * 8);
    size_t required = off;

    const int tb = 256;
    float* out = (float*)d_out;

    if (ws_size < required) {
        ctm_fallback<<<(out_size + tb - 1) / tb, tb, 0, stream>>>(out, out_size);
        return;
    }

    double* xmap56  = arena;
    double* xmerged = arena;   // reused after conv; re-zeroed below

    hipMemsetAsync(d_ws, 0, zero_bytes, stream);

    ctm_prep<<<(BNq + tb - 1) / tb, tb, 0, stream>>>(loc, idxag, aggw, cell56, cell28, cnt56, allwtok);
    ctm_t2m<<<(BNq + tb - 1) / tb, tb, 0, stream>>>(x, idxag, cell56, cnt56, xmap56);
    ctm_conv<<<((Bq * C2q * HOq * WOq) + tb - 1) / tb, tb, 0, stream>>>(xmap56, convw, convb, xmap28);
    ctm_m2t<<<(BNq + tb - 1) / tb, tb, 0, stream>>>(xmap28, aggw, idxag, cell28, allwtok, xt);
    ctm_finalize<<<BNq, C2q, 0, stream>>>(xt, x, skipw, lng, lnb, confw, confb, x2, weightv);
    ctm_pass1<<<Bq * NIT64 * NSPL, 256, 0, stream>>>(xt, x2, pbest, pmax);
    ctm_merge1<<<(BNq + tb - 1) / tb, tb, 0, stream>>>(pbest, pmax, density, rowmax2);
    ctm_rowmax<<<Bq, 256, 0, stream>>>(rowmax2, maxd2);
    ctm_pass2<<<Bq * NIT64 * NSPL, 256, 0, stream>>>(xt, x2, density, pmin);
    ctm_merge2<<<(BNq + tb - 1) / tb, tb, 0, stream>>>(pmin, maxd2, density, score);
    ctm_sort<<<Bq, 1024, 0, stream>>>(score, indexdn);
    ctm_assign<<<Bq * NIT64, 256, 0, stream>>>(xt, x2, indexdn, idxclu);
    ctm_override<<<((Bq * NSq) + tb - 1) / tb, tb, 0, stream>>>(indexdn, idxclu);
    ctm_zeromerged<<<((Bq * NSq * C2q) + tb - 1) / tb, tb, 0, stream>>>(xmerged);
    ctm_merge_w<<<(BNq + tb - 1) / tb, tb, 0, stream>>>(idxclu, weightv, allwc);
    ctm_merge_x<<<(BNq + tb - 1) / tb, tb, 0, stream>>>(idxclu, weightv, allwc, xt, nw, xmerged);

    ctm_out0<<<((Bq * NSq * C2q) + tb - 1) / tb, tb, 0, stream>>>(xmerged, out);
    ctm_out12<<<(BNq + tb - 1) / tb, tb, 0, stream>>>(idxag, idxclu, nw, aggw,
                                                      out + (size_t)Bq * NSq * C2q, awd, maxawd);
    ctm_out2<<<(BNq + tb - 1) / tb, tb, 0, stream>>>(awd, maxawd,
                                                     out + (size_t)Bq * NSq * C2q + BNq);
}

// Round 14
// 2043.783 us; speedup vs baseline: 1.0114x; 1.0114x over previous
//
#include <hip/hip_runtime.h>
#include <math.h>
#include <float.h>

// Problem constants: B=4, N=3136, C=64, C2=128, H=W=56, stride2 -> 28x28,
// Ns = ceil(N*0.25) = 784, k = 5.  Inputs are float32/int32 per reference.
#define Bq   4
#define Nq   3136
#define Cq   64
#define C2q  128
#define Hq   56
#define Wq   56
#define HWq  (Hq*Wq)
#define HOq  28
#define WOq  28
#define HWOq (HOq*WOq)
#define NSq  784
#define KNN  5
#define BNq  (Bq*Nq)

#define T64   64             // i/j tile for distance kernels
#define KC    32             // K chunk
#define NIT64 (Nq/T64)       // 49 i-tiles (exact)
#define NT_C  ((NSq+T64-1)/T64) // 13 center tiles (last partial)
#define NSPL  4              // j-range splits (grid 784)
#define LDP   34             // LDS row stride (even -> 16B-aligned double2)

__device__ __constant__ int c_spl[NSPL + 1] = {0, 13, 25, 37, 49};

typedef unsigned int   u32;
typedef unsigned long long u64;

static __device__ __forceinline__ void atomicMaxPosD(double* p, double v) {
    atomicMax((u64*)p, (u64)__double_as_longlong(v));
}
static __device__ __forceinline__ int clampTok(int t) {
    return min(max(t, 0), Nq - 1);
}

// sorted-ascending insert into 5-list (static indices after unroll)
static __device__ __forceinline__ void ins5(double* a, double v) {
    if (v < a[KNN - 1]) {
        a[KNN - 1] = v;
        #pragma unroll
        for (int m = KNN - 1; m > 0; m--)
            if (a[m] < a[m - 1]) { double t = a[m]; a[m] = a[m - 1]; a[m - 1] = t; }
    }
}
// compare-exchange (branch-free, static)
static __device__ __forceinline__ void cex(double& a, double& b) {
    double lo = fmin(a, b), hi = fmax(a, b); a = lo; b = hi;
}
// merge two ascending 5-lists, keep 5 smallest ascending.
// STATIC INDICES ONLY (SROA -> VGPRs; dynamic idx caused 338 MB spill, R7/R8).
static __device__ __forceinline__ void merge5(double* a, const double* p) {
    double t0 = fmin(a[0], p[4]);
    double t1 = fmin(a[1], p[3]);
    double t2 = fmin(a[2], p[2]);
    double t3 = fmin(a[3], p[1]);
    double t4 = fmin(a[4], p[0]);
    cex(t0, t1); cex(t1, t2); cex(t2, t3); cex(t3, t4);
    cex(t0, t1); cex(t1, t2); cex(t2, t3);
    cex(t0, t1); cex(t1, t2);
    cex(t0, t1);
    a[0] = t0; a[1] = t1; a[2] = t2; a[3] = t3; a[4] = t4;
}

// ---- jax threefry2x32 noise: uniform(key(42), (4,3136)) -------------------
static __device__ __forceinline__ u32 rotl32(u32 x, int d) { return (x << d) | (x >> (32 - d)); }
static __device__ __forceinline__ float tf_uniform(int t) {
    const u32 k0 = 0u, k1 = 42u;
    const u32 ks2 = k0 ^ k1 ^ 0x1BD11BDAu;
    u32 ks[3] = { k0, k1, ks2 };
    bool lo = (t < 6272);
    u32 cx0 = lo ? (u32)t : (u32)(t - 6272);
    u32 cx1 = lo ? (u32)(t + 6272) : (u32)t;
    u32 x0 = cx0 + ks[0];
    u32 x1 = cx1 + ks[1];
    const int R0[4] = {13, 15, 26, 6};
    const int R1[4] = {17, 29, 16, 24};
    #pragma unroll
    for (int i = 0; i < 5; i++) {
        const int* rot = (i % 2 == 0) ? R0 : R1;
        #pragma unroll
        for (int r = 0; r < 4; r++) { x0 += x1; x1 = rotl32(x1, rot[r]); x1 ^= x0; }
        x0 += ks[(i + 1) % 3];
        x1 += ks[(i + 2) % 3] + (u32)(i + 1);
    }
    u32 bits = lo ? x0 : x1;
    u32 fb = (bits >> 9) | 0x3f800000u;
    float f; __builtin_memcpy(&f, &fb, 4);
    return f - 1.0f;
}

// ---- grid index: clip(loc,-1,1)*0.5+0.5 -> round-half-even ----------------
static __device__ __forceinline__ int gridIndex(float lx, float ly, int Wd, int Hd) {
    double x = fmin(fmax((double)lx, -1.0), 1.0) * 0.5 + 0.5;
    double y = fmin(fmax((double)ly, -1.0), 1.0) * 0.5 + 0.5;
    int ix = (int)rint(x * (double)(Wd - 1)); ix = min(max(ix, 0), Wd - 1);
    int iy = (int)rint(y * (double)(Hd - 1)); iy = min(max(iy, 0), Hd - 1);
    return iy * Wd + ix;
}

// ---------------------------------------------------------------------------
__global__ void ctm_fallback(float* out, int n) {
    int t = blockIdx.x * blockDim.x + threadIdx.x;
    if (t < n) out[t] = 0.0f;
}

__global__ void ctm_prep(const float* __restrict__ loc, const int* __restrict__ idx_agg,
                         const float* __restrict__ aggw,
                         int* cell56, int* cell28, int* cnt56, double* allwtok) {
    int t = blockIdx.x * blockDim.x + threadIdx.x;
    if (t >= BNq) return;
    int b = t / Nq;
    float lx = loc[2 * t], ly = loc[2 * t + 1];
    int c56 = gridIndex(lx, ly, Wq, Hq);
    int c28 = gridIndex(lx, ly, WOq, HOq);
    cell56[t] = c56; cell28[t] = c28;
    atomicAdd(&cnt56[b * HWq + c56], 1);
    int tok = clampTok(idx_agg[t]);
    atomicAdd(&allwtok[b * Nq + tok], (double)aggw[t]);
}

// t2m, (point,channel)-parallel: one coalesced f64 atomic per thread into the
// channel-contiguous transposed map xmap56T[b][cell][c].
__global__ void ctm_t2m(const float* __restrict__ x, const int* __restrict__ idx_agg,
                        const int* __restrict__ cell56, const int* __restrict__ cnt56,
                        double* xmap56T) {
    int id = blockIdx.x * blockDim.x + threadIdx.x;
    if (id >= BNq * Cq) return;
    int t = id / Cq, c = id - t * Cq;
    int b = t / Nq;
    int cell = cell56[t];
    double v = 1.0 / ((double)cnt56[b * HWq + cell] + 1e-6);
    double xv = (double)x[(size_t)(b * Nq + clampTok(idx_agg[t])) * Cq + c];
    atomicAdd(&xmap56T[((size_t)b * HWq + cell) * Cq + c], xv * v);
}

// conv 3x3 stride2 on transposed layouts: in xmap56T[b][cell][ci],
// out xmap28T[b][cell][co]. Threads: co fastest -> coalesced writes,
// wave-broadcast input reads.
__global__ void ctm_conv(const double* __restrict__ xmap56T, const float* __restrict__ w,
                         const float* __restrict__ bias, double* xmap28T) {
    int t = blockIdx.x * blockDim.x + threadIdx.x;
    if (t >= Bq * HWOq * C2q) return;
    int co = t % C2q;
    int cell = (t / C2q) % HWOq;
    int b = t / (C2q * HWOq);
    int ox = cell % WOq, oy = cell / WOq;
    double acc = (double)bias[co];
    const float* wr = w + (size_t)co * Cq * 9;
    const double* xb = xmap56T + (size_t)b * HWq * Cq;
    #pragma unroll 4
    for (int ci = 0; ci < Cq; ci++) {
        const float* wc = wr + ci * 9;
        for (int ky = 0; ky < 3; ky++) {
            int iy = 2 * oy + ky - 1; if (iy < 0 || iy >= Hq) continue;
            for (int kx = 0; kx < 3; kx++) {
                int ix = 2 * ox + kx - 1; if (ix < 0 || ix >= Wq) continue;
                acc += xb[(size_t)(iy * Wq + ix) * Cq + ci] * (double)wc[ky * 3 + kx];
            }
        }
    }
    xmap28T[((size_t)b * HWOq + cell) * C2q + co] = acc;
}

// m2t, (point,channel)-parallel: coalesced reads from xmap28T, one coalesced
// f64 atomic per thread into xt[tok][c].
__global__ void ctm_m2t(const double* __restrict__ xmap28T, const float* __restrict__ aggw,
                        const int* __restrict__ idx_agg, const int* __restrict__ cell28,
                        const double* __restrict__ allwtok, double* xt) {
    int id = blockIdx.x * blockDim.x + threadIdx.x;
    if (id >= BNq * C2q) return;
    int t = id / C2q, c = id - t * C2q;
    int b = t / Nq;
    int tok = clampTok(idx_agg[t]);
    double v = (double)aggw[t] / (allwtok[b * Nq + tok] + 1e-6);
    double f = xmap28T[((size_t)b * HWOq + cell28[t]) * C2q + c];
    atomicAdd(&xt[(size_t)(b * Nq + tok) * C2q + c], f * v);
}

__global__ __launch_bounds__(C2q)
void ctm_finalize(double* xt, const float* __restrict__ x, const float* __restrict__ skipw,
                  const float* __restrict__ lng, const float* __restrict__ lnb,
                  const float* __restrict__ confw, const float* __restrict__ confb,
                  double* x2o, double* weightv) {
    int bn = blockIdx.x; int c = threadIdx.x;
    double* row = xt + (size_t)bn * C2q;
    const float* xr = x + (size_t)bn * Cq;
    double acc = row[c];
    const float* sw = skipw + c * Cq;
    #pragma unroll 16
    for (int k = 0; k < Cq; k++) acc += (double)xr[k] * (double)sw[k];
    __shared__ double red[C2q];
    __shared__ double stat[2];
    red[c] = acc; __syncthreads();
    for (int off = C2q / 2; off > 0; off >>= 1) { if (c < off) red[c] += red[c + off]; __syncthreads(); }
    if (c == 0) stat[0] = red[0] * (1.0 / C2q);
    __syncthreads();
    double mu = stat[0];
    double d = acc - mu;
    red[c] = d * d; __syncthreads();
    for (int off = C2q / 2; off > 0; off >>= 1) { if (c < off) red[c] += red[c + off]; __syncthreads(); }
    if (c == 0) stat[1] = red[0] * (1.0 / C2q);
    __syncthreads();
    double var = stat[1];
    double v = d / sqrt(var + 1e-5) * (double)lng[c] + (double)lnb[c];
    row[c] = v;
    red[c] = v * v; __syncthreads();
    for (int off = C2q / 2; off > 0; off >>= 1) { if (c < off) red[c] += red[c + off]; __syncthreads(); }
    if (c == 0) x2o[bn] = red[0];
    __syncthreads();
    red[c] = v * (double)confw[c]; __syncthreads();
    for (int off = C2q / 2; off > 0; off >>= 1) { if (c < off) red[c] += red[c + off]; __syncthreads(); }
    if (c == 0) weightv[bn] = exp(red[0] + (double)confb[0]);
}

// ---------------------------------------------------------------------------
// Distance kernels v2.5: (256,2) = VGPR 84, no spill (R10-R12 evidence) plus
// XCD-aware block swizzle: batch b is the FASTEST block index. Blocks
// round-robin over the 8 XCDs, so each XCD hosts a single batch's xt
// (3.2 MB < 4 MB L2) -- R12's s-fastest order mixed all 4 batches per XCD
// (12.8 MB) and thrashed L2 (FETCH 288 MB/dispatch). Bit-identical
// arithmetic (c ascending per pair).
// ---------------------------------------------------------------------------

// pass1: per row i -> 5 smallest d2 + row max d2 (partial per j-split)
__global__ __launch_bounds__(256, 2)
void ctm_pass1(const double* __restrict__ xt, const double* __restrict__ x2,
               double* pbest, double* pmax) {
    __shared__ double sA[T64][LDP];
    __shared__ double sB[T64][LDP];
    __shared__ double sx2j[T64];
    int blk = blockIdx.x;
    int b  = blk & (Bq - 1);
    int s  = (blk >> 2) & (NSPL - 1);
    int it = blk >> 4;
    int tid = threadIdx.x, tx = tid & 15, ty = tid >> 4;
    const double* xtb = xt + (size_t)b * Nq * C2q;
    const double* x2b = x2 + (size_t)b * Nq;
    int i0 = it * T64;
    double x2i[4];
    #pragma unroll
    for (int r = 0; r < 4; r++) x2i[r] = x2b[i0 + ty + 16 * r];
    double best[4][KNN]; double mx[4];
    #pragma unroll
    for (int r = 0; r < 4; r++) {
        mx[r] = -DBL_MAX;
        #pragma unroll
        for (int k = 0; k < KNN; k++) best[r][k] = DBL_MAX;
    }
    int jt_beg = c_spl[s], jt_end = c_spl[s + 1];
    for (int jt = jt_beg; jt < jt_end; jt++) {
        int j0 = jt * T64;
        double acc[4][4];
        #pragma unroll
        for (int r = 0; r < 4; r++)
            #pragma unroll
            for (int q = 0; q < 4; q++) acc[r][q] = 0.0;
        for (int kc = 0; kc < 4; kc++) {
            __syncthreads();
            for (int idx = tid; idx < T64 * KC; idx += 256) {
                int r = idx >> 5, c = idx & 31;
                sA[r][c] = xtb[(size_t)(i0 + r) * C2q + kc * KC + c];
                sB[r][c] = xtb[(size_t)(j0 + r) * C2q + kc * KC + c];
            }
            if (kc == 0 && tid < T64) sx2j[tid] = x2b[j0 + tid];
            __syncthreads();
            #pragma unroll 4
            for (int cc = 0; cc < KC; cc += 2) {
                double2 xi[4], xj[4];
                #pragma unroll
                for (int r = 0; r < 4; r++) xi[r] = *(const double2*)&sA[ty + 16 * r][cc];
                #pragma unroll
                for (int q = 0; q < 4; q++) xj[q] = *(const double2*)&sB[tx + 16 * q][cc];
                #pragma unroll
                for (int r = 0; r < 4; r++)
                    #pragma unroll
                    for (int q = 0; q < 4; q++) acc[r][q] += xi[r].x * xj[q].x;
                #pragma unroll
                for (int r = 0; r < 4; r++)
                    #pragma unroll
                    for (int q = 0; q < 4; q++) acc[r][q] += xi[r].y * xj[q].y;
            }
        }
        #pragma unroll
        for (int r = 0; r < 4; r++)
            #pragma unroll
            for (int q = 0; q < 4; q++) {
                double d2 = x2i[r] + sx2j[tx + 16 * q] - 2.0 * acc[r][q];
                mx[r] = fmax(mx[r], d2);
                ins5(best[r], d2);
            }
    }
    for (int m = 1; m <= 8; m <<= 1) {
        #pragma unroll
        for (int r = 0; r < 4; r++) {
            double p[KNN];
            #pragma unroll
            for (int k = 0; k < KNN; k++) p[k] = __shfl_xor(best[r][k], m);
            mx[r] = fmax(mx[r], __shfl_xor(mx[r], m));
            merge5(best[r], p);
        }
    }
    if (tx == 0) {
        #pragma unroll
        for (int r = 0; r < 4; r++) {
            int gi = b * Nq + i0 + ty + 16 * r;
            size_t base = ((size_t)s * BNq + gi) * KNN;
            #pragma unroll
            for (int k = 0; k < KNN; k++) pbest[base + k] = best[r][k];
            pmax[(size_t)s * BNq + gi] = mx[r];
        }
    }
}

// merge pass1 partials -> density + rowmax2
__global__ void ctm_merge1(const double* __restrict__ pbest, const double* __restrict__ pmax,
                           double* density, double* rowmax2) {
    int t = blockIdx.x * blockDim.x + threadIdx.x;
    if (t >= BNq) return;
    double a[KNN];
    #pragma unroll
    for (int k = 0; k < KNN; k++) a[k] = pbest[(size_t)t * KNN + k];
    double mxv = pmax[t];
    #pragma unroll
    for (int s = 1; s < NSPL; s++) {
        double p[KNN];
        #pragma unroll
        for (int k = 0; k < KNN; k++) p[k] = pbest[((size_t)s * BNq + t) * KNN + k];
        merge5(a, p);
        mxv = fmax(mxv, pmax[(size_t)s * BNq + t]);
    }
    double sum = 0.0;
    #pragma unroll
    for (int k = 0; k < KNN; k++) sum += fmax(a[k], 0.0);
    density[t] = exp(-sum / (double)(C2q * KNN)) + (double)(tf_uniform(t) * 1e-6f);
    rowmax2[t] = mxv;
}

__global__ __launch_bounds__(256)
void ctm_rowmax(const double* __restrict__ rowmax2, double* maxd2) {
    int b = blockIdx.x, tid = threadIdx.x;
    double m = -DBL_MAX;
    for (int i = tid; i < Nq; i += 256) m = fmax(m, rowmax2[b * Nq + i]);
    __shared__ double sm[256];
    sm[tid] = m; __syncthreads();
    for (int off = 128; off > 0; off >>= 1) { if (tid < off) sm[tid] = fmax(sm[tid], sm[tid + off]); __syncthreads(); }
    if (tid == 0) maxd2[b] = sm[0];
}

// pass2: min d2 over higher-density j (partial per j-split)
__global__ __launch_bounds__(256, 2)
void ctm_pass2(const double* __restrict__ xt, const double* __restrict__ x2,
               const double* __restrict__ density, double* pmin) {
    __shared__ double sA[T64][LDP];
    __shared__ double sB[T64][LDP];
    __shared__ double sx2j[T64];
    __shared__ double sdj[T64];
    int blk = blockIdx.x;
    int b  = blk & (Bq - 1);
    int s  = (blk >> 2) & (NSPL - 1);
    int it = blk >> 4;
    int tid = threadIdx.x, tx = tid & 15, ty = tid >> 4;
    const double* xtb = xt + (size_t)b * Nq * C2q;
    const double* x2b = x2 + (size_t)b * Nq;
    const double* db  = density + (size_t)b * Nq;
    int i0 = it * T64;
    double x2i[4], di[4], mn[4];
    #pragma unroll
    for (int r = 0; r < 4; r++) {
        x2i[r] = x2b[i0 + ty + 16 * r];
        di[r]  = db[i0 + ty + 16 * r];
        mn[r]  = DBL_MAX;
    }
    int jt_beg = c_spl[s], jt_end = c_spl[s + 1];
    for (int jt = jt_beg; jt < jt_end; jt++) {
        int j0 = jt * T64;
        double acc[4][4];
        #pragma unroll
        for (int r = 0; r < 4; r++)
            #pragma unroll
            for (int q = 0; q < 4; q++) acc[r][q] = 0.0;
        for (int kc = 0; kc < 4; kc++) {
            __syncthreads();
            for (int idx = tid; idx < T64 * KC; idx += 256) {
                int r = idx >> 5, c = idx & 31;
                sA[r][c] = xtb[(size_t)(i0 + r) * C2q + kc * KC + c];
                sB[r][c] = xtb[(size_t)(j0 + r) * C2q + kc * KC + c];
            }
            if (kc == 0 && tid < T64) { sx2j[tid] = x2b[j0 + tid]; sdj[tid] = db[j0 + tid]; }
            __syncthreads();
            #pragma unroll 4
            for (int cc = 0; cc < KC; cc += 2) {
                double2 xi[4], xj[4];
                #pragma unroll
                for (int r = 0; r < 4; r++) xi[r] = *(const double2*)&sA[ty + 16 * r][cc];
                #pragma unroll
                for (int q = 0; q < 4; q++) xj[q] = *(const double2*)&sB[tx + 16 * q][cc];
                #pragma unroll
                for (int r = 0; r < 4; r++)
                    #pragma unroll
                    for (int q = 0; q < 4; q++) acc[r][q] += xi[r].x * xj[q].x;
                #pragma unroll
                for (int r = 0; r < 4; r++)
                    #pragma unroll
                    for (int q = 0; q < 4; q++) acc[r][q] += xi[r].y * xj[q].y;
            }
        }
        #pragma unroll
        for (int r = 0; r < 4; r++)
            #pragma unroll
            for (int q = 0; q < 4; q++) {
                double d2 = x2i[r] + sx2j[tx + 16 * q] - 2.0 * acc[r][q];
                if (sdj[tx + 16 * q] > di[r]) mn[r] = fmin(mn[r], d2);
            }
    }
    for (int m = 1; m <= 8; m <<= 1) {
        #pragma unroll
        for (int r = 0; r < 4; r++) mn[r] = fmin(mn[r], __shfl_xor(mn[r], m));
    }
    if (tx == 0) {
        #pragma unroll
        for (int r = 0; r < 4; r++) {
            int gi = b * Nq + i0 + ty + 16 * r;
            pmin[(size_t)s * BNq + gi] = mn[r];
        }
    }
}

// merge pass2 partials -> score
__global__ void ctm_merge2(const double* __restrict__ pmin, const double* __restrict__ maxd2,
                           const double* __restrict__ density, double* score) {
    int t = blockIdx.x * blockDim.x + threadIdx.x;
    if (t >= BNq) return;
    int b = t / Nq;
    double m = pmin[t];
    #pragma unroll
    for (int s = 1; s < NSPL; s++) m = fmin(m, pmin[(size_t)s * BNq + t]);
    double mm = fmin(maxd2[b], m);
    score[t] = sqrt(fmax(mm, 0.0)) / sqrt((double)C2q) * density[t];
}

// top-784 with jax.lax.top_k semantics: total order (score desc, idx asc).
__global__ __launch_bounds__(1024)
void ctm_sort(const double* __restrict__ score, int* index_down) {
    __shared__ double s[4096];
    __shared__ int   si[4096];
    int b = blockIdx.x, tid = threadIdx.x;
    for (int i = tid; i < 4096; i += 1024) {
        if (i < Nq) {
            double v = score[b * Nq + i];
            s[i] = isnan(v) ? -DBL_MAX : v;
            si[i] = i;
        } else { s[i] = -DBL_MAX; si[i] = 0x7fffffff; }
    }
    __syncthreads();
    for (int k = 2; k <= 4096; k <<= 1) {
        for (int j = k >> 1; j > 0; j >>= 1) {
            for (int i = tid; i < 4096; i += 1024) {
                int ixj = i ^ j;
                if (ixj > i) {
                    double s1 = s[i], s2 = s[ixj];
                    int i1 = si[i], i2 = si[ixj];
                    bool before_ij = (s1 > s2) || (s1 == s2 && i1 < i2);
                    bool before_ji = (s2 > s1) || (s2 == s1 && i2 < i1);
                    bool doswap = ((i & k) == 0) ? before_ji : before_ij;
                    if (doswap) { s[i] = s2; s[ixj] = s1; si[i] = i2; si[ixj] = i1; }
                }
            }
            __syncthreads();
        }
    }
    for (int t = tid; t < NSq; t += 1024) {
        int v = si[t];
        index_down[b * NSq + t] = ((unsigned)v < (unsigned)Nq) ? v : 0;
    }
}

// assign: argmin over 784 centers, tie-break smallest sc (lexicographic d,sc)
__global__ __launch_bounds__(256, 2)
void ctm_assign(const double* __restrict__ xt, const double* __restrict__ x2,
                const int* __restrict__ index_down, int* idx_cluster) {
    __shared__ double sA[T64][LDP];
    __shared__ double sB[T64][LDP];
    __shared__ double sx2c[T64];
    __shared__ int    sidx[T64];
    int blk = blockIdx.x;
    int b  = blk & (Bq - 1);
    int it = blk >> 2;
    int tid = threadIdx.x, tx = tid & 15, ty = tid >> 4;
    const double* xtb = xt + (size_t)b * Nq * C2q;
    const double* x2b = x2 + (size_t)b * Nq;
    int i0 = it * T64;
    double x2i[4], bd[4];
    int bs[4];
    #pragma unroll
    for (int r = 0; r < 4; r++) { x2i[r] = x2b[i0 + ty + 16 * r]; bd[r] = DBL_MAX; bs[r] = NSq - 1; }
    for (int jt = 0; jt < NT_C; jt++) {
        int j0 = jt * T64;
        __syncthreads();
        if (tid < T64) {
            int j = index_down[b * NSq + min(j0 + tid, NSq - 1)];
            sidx[tid] = j;
            sx2c[tid] = x2b[j];
        }
        __syncthreads();
        double acc[4][4];
        #pragma unroll
        for (int r = 0; r < 4; r++)
            #pragma unroll
            for (int q = 0; q < 4; q++) acc[r][q] = 0.0;
        for (int kc = 0; kc < 4; kc++) {
            if (kc) __syncthreads();
            for (int idx = tid; idx < T64 * KC; idx += 256) {
                int r = idx >> 5, c = idx & 31;
                sA[r][c] = xtb[(size_t)(i0 + r) * C2q + kc * KC + c];
                sB[r][c] = xtb[(size_t)sidx[r] * C2q + kc * KC + c];
            }
            __syncthreads();
            #pragma unroll 4
            for (int cc = 0; cc < KC; cc += 2) {
                double2 xi[4], xj[4];
                #pragma unroll
                for (int r = 0; r < 4; r++) xi[r] = *(const double2*)&sA[ty + 16 * r][cc];
                #pragma unroll
                for (int q = 0; q < 4; q++) xj[q] = *(const double2*)&sB[tx + 16 * q][cc];
                #pragma unroll
                for (int r = 0; r < 4; r++)
                    #pragma unroll
                    for (int q = 0; q < 4; q++) acc[r][q] += xi[r].x * xj[q].x;
                #pragma unroll
                for (int r = 0; r < 4; r++)
                    #pragma unroll
                    for (int q = 0; q < 4; q++) acc[r][q] += xi[r].y * xj[q].y;
            }
        }
        #pragma unroll
        for (int r = 0; r < 4; r++)
            #pragma unroll
            for (int q = 0; q < 4; q++) {
                int sc = j0 + tx + 16 * q;
                double d = fmax(x2i[r] + sx2c[tx + 16 * q] - 2.0 * acc[r][q], 0.0);
                if (sc < NSq && (d < bd[r] || (d == bd[r] && sc < bs[r]))) { bd[r] = d; bs[r] = sc; }
            }
    }
    for (int m = 1; m <= 8; m <<= 1) {
        #pragma unroll
        for (int r = 0; r < 4; r++) {
            double pd = __shfl_xor(bd[r], m);
            int    ps = __shfl_xor(bs[r], m);
            if (pd < bd[r] || (pd == bd[r] && ps < bs[r])) { bd[r] = pd; bs[r] = ps; }
        }
    }
    if (tx == 0) {
        #pragma unroll
        for (int r = 0; r < 4; r++) idx_cluster[b * Nq + i0 + ty + 16 * r] = bs[r];
    }
}

__global__ void ctm_override(const int* __restrict__ index_down, int* idx_cluster) {
    int t = blockIdx.x * blockDim.x + threadIdx.x;
    if (t >= Bq * NSq) return;
    int b = t / NSq, sc = t - b * NSq;
    int j = index_down[t];
    if ((unsigned)j < (unsigned)Nq) idx_cluster[b * Nq + j] = sc;
}

__global__ void ctm_zeromerged(double* xmerged) {
    int t = blockIdx.x * blockDim.x + threadIdx.x;
    if (t < Bq * NSq * C2q) xmerged[t] = 0.0;
}

__global__ void ctm_merge_w(const int* __restrict__ idx_cluster, const double* __restrict__ weightv,
                            double* allwc) {
    int t = blockIdx.x * blockDim.x + threadIdx.x;
    if (t >= BNq) return;
    int b = t / Nq;
    int sc = min(max(idx_cluster[t], 0), NSq - 1);
    atomicAdd(&allwc[b * NSq + sc], weightv[t]);
}

// merge_x, (point,channel)-parallel: one coalesced atomic per thread.
__global__ void ctm_merge_x(const int* __restrict__ idx_cluster, const double* __restrict__ weightv,
                            const double* __restrict__ allwc, const double* __restrict__ xt,
                            double* nw, double* xmerged) {
    int id = blockIdx.x * blockDim.x + threadIdx.x;
    if (id >= BNq * C2q) return;
    int t = id / C2q, c = id - t * C2q;
    int b = t / Nq;
    int sc = min(max(idx_cluster[t], 0), NSq - 1);
    double nv = weightv[t] / (allwc[b * NSq + sc] + 1e-6);
    if (c == 0) nw[t] = nv;
    atomicAdd(&xmerged[((size_t)(b * NSq + sc)) * C2q + c], xt[(size_t)t * C2q + c] * nv);
}

__global__ void ctm_out0(const double* __restrict__ xmerged, float* out) {
    int t = blockIdx.x * blockDim.x + threadIdx.x;
    if (t >= Bq * NSq * C2q) return;
    out[t] = (float)xmerged[t];
}

__global__ void ctm_out12(const int* __restrict__ idx_agg, const int* __restrict__ idx_cluster,
                          const double* __restrict__ nw, const float* __restrict__ aggw,
                          float* out1, double* awd, double* maxawd) {
    int t = blockIdx.x * blockDim.x + threadIdx.x;
    if (t >= BNq) return;
    int b = t / Nq;
    int tok = clampTok(idx_agg[t]);
    int sc = idx_cluster[b * Nq + tok];
    out1[t] = (float)sc;
    double a = (double)aggw[t] * nw[b * Nq + tok];
    awd[t] = a;
    atomicMaxPosD(&maxawd[b], a);
}

__global__ void ctm_out2(const double* __restrict__ awd, const double* __restrict__ maxawd, float* out2) {
    int t = blockIdx.x * blockDim.x + threadIdx.x;
    if (t >= BNq) return;
    int b = t / Nq;
    out2[t] = (float)(awd[t] / maxawd[b]);
}

// ---------------------------------------------------------------------------
extern "C" void kernel_launch(void* const* d_in, const int* in_sizes, int n_in,
                              void* d_out, int out_size, void* d_ws, size_t ws_size,
                              hipStream_t stream) {
    const float* x     = (const float*)d_in[0];
    const float* loc   = (const float*)d_in[1];
    const int*   idxag = (const int*)  d_in[2];
    const float* aggw  = (const float*)d_in[3];
    const float* convw = (const float*)d_in[4];
    const float* convb = (const float*)d_in[5];
    const float* skipw = (const float*)d_in[6];
    const float* lng   = (const float*)d_in[7];
    const float* lnb   = (const float*)d_in[8];
    const float* confw = (const float*)d_in[9];
    const float* confb = (const float*)d_in[10];
    (void)in_sizes; (void)n_in;

    char* w = (char*)d_ws;
    size_t off = 0;
    auto alloc = [&](size_t bytes) -> void* {
        void* p = w + off; off = (off + bytes + 255) & ~(size_t)255; return p;
    };

    // ---- zero-initialized region (one memset) ----
    int*    cnt56   = (int*)   alloc((size_t)BNq * 4);
    double* allwtok = (double*)alloc((size_t)BNq * 8);
    double* xt      = (double*)alloc((size_t)BNq * C2q * 8);
    double* arena   = (double*)alloc((size_t)Bq * HWq * Cq * 8);   // xmap56T, later xmerged
    double* allwc   = (double*)alloc((size_t)Bq * NSq * 8);
    double* maxawd  = (double*)alloc((size_t)Bq * 8);
    size_t zero_bytes = off;
    // ---- non-zero region ----
    int*    cell56   = (int*)   alloc((size_t)BNq * 4);
    int*    cell28   = (int*)   alloc((size_t)BNq * 4);
    double* xmap28T  = (double*)alloc((size_t)Bq * HWOq * C2q * 8);
    double* x2       = (double*)alloc((size_t)BNq * 8);
    double* density  = (double*)alloc((size_t)BNq * 8);
    double* rowmax2  = (double*)alloc((size_t)BNq * 8);
    double* maxd2    = (double*)alloc((size_t)Bq * 8);
    double* score    = (double*)alloc((size_t)BNq * 8);
    int*    indexdn  = (int*)   alloc((size_t)Bq * NSq * 4);
    int*    idxclu   = (int*)   alloc((size_t)BNq * 4);
    double* nw       = (double*)alloc((size_t)BNq * 8);
    double* weightv  = (double*)alloc((size_t)BNq * 8);
    double* awd      = (double*)alloc((size_t)BNq * 8);
    double* pbest    = (double*)alloc((size_t)NSPL * BNq * KNN * 8);
    double* pmax     = (double*)alloc((size_t)NSPL * BNq * 8);
    double* pmin     = (double*)alloc((size_t)NSPL * BNq * 8);
    size_t required = off;

    const int tb = 256;
    float* out = (float*)d_out;

    if (ws_size < required) {
        ctm_fallback<<<(out_size + tb - 1) / tb, tb, 0, stream>>>(out, out_size);
        return;
    }

    double* xmap56T = arena;
    double* xmerged = arena;   // reused after conv; re-zeroed below

    hipMemsetAsync(d_ws, 0, zero_bytes, stream);

    ctm_prep<<<(BNq + tb - 1) / tb, tb, 0, stream>>>(loc, idxag, aggw, cell56, cell28, cnt56, allwtok);
    ctm_t2m<<<((BNq * Cq) + tb - 1) / tb, tb, 0, stream>>>(x, idxag, cell56, cnt56, xmap56T);
    ctm_conv<<<((Bq * HWOq * C2q) + tb - 1) / tb, tb, 0, stream>>>(xmap56T, convw, convb, xmap28T);
    ctm_m2t<<<((BNq * C2q) + tb - 1) / tb, tb, 0, stream>>>(xmap28T, aggw, idxag, cell28, allwtok, xt);
    ctm_finalize<<<BNq, C2q, 0, stream>>>(xt, x, skipw, lng, lnb, confw, confb, x2, weightv);
    ctm_pass1<<<Bq * NIT64 * NSPL, 256, 0, stream>>>(xt, x2, pbest, pmax);
    ctm_merge1<<<(BNq + tb - 1) / tb, tb, 0, stream>>>(pbest, pmax, density, rowmax2);
    ctm_rowmax<<<Bq, 256, 0, stream>>>(rowmax2, maxd2);
    ctm_pass2<<<Bq * NIT64 * NSPL, 256, 0, stream>>>(xt, x2, density, pmin);
    ctm_merge2<<<(BNq + tb - 1) / tb, tb, 0, stream>>>(pmin, maxd2, density, score);
    ctm_sort<<<Bq, 1024, 0, stream>>>(score, indexdn);
    ctm_assign<<<Bq * NIT64, 256, 0, stream>>>(xt, x2, indexdn, idxclu);
    ctm_override<<<((Bq * NSq) + tb - 1) / tb, tb, 0, stream>>>(indexdn, idxclu);
    ctm_zeromerged<<<((Bq * NSq * C2q) + tb - 1) / tb, tb, 0, stream>>>(xmerged);
    ctm_merge_w<<<(BNq + tb - 1) / tb, tb, 0, stream>>>(idxclu, weightv, allwc);
    ctm_merge_x<<<((BNq * C2q) + tb - 1) / tb, tb, 0, stream>>>(idxclu, weightv, allwc, xt, nw, xmerged);

    ctm_out0<<<((Bq * NSq * C2q) + tb - 1) / tb, tb, 0, stream>>>(xmerged, out);
    ctm_out12<<<(BNq + tb - 1) / tb, tb, 0, stream>>>(idxag, idxclu, nw, aggw,
                                                      out + (size_t)Bq * NSq * C2q, awd, maxawd);
    ctm_out2<<<(BNq + tb - 1) / tb, tb, 0, stream>>>(awd, maxawd,
                                                     out + (size_t)Bq * NSq * C2q + BNq);
}

// Round 15
// 1492.919 us; speedup vs baseline: 1.3846x; 1.3690x over previous
//
#include <hip/hip_runtime.h>
#include <math.h>
#include <float.h>

// Problem constants: B=4, N=3136, C=64, C2=128, H=W=56, stride2 -> 28x28,
// Ns = ceil(N*0.25) = 784, k = 5.  Inputs are float32/int32 per reference.
#define Bq   4
#define Nq   3136
#define Cq   64
#define C2q  128
#define Hq   56
#define Wq   56
#define HWq  (Hq*Wq)
#define HOq  28
#define WOq  28
#define HWOq (HOq*WOq)
#define NSq  784
#define KNN  5
#define BNq  (Bq*Nq)

#define T64   64             // i/j tile for distance kernels
#define KC    32             // K chunk
#define NIT64 (Nq/T64)       // 49 i-tiles (exact)
#define NT_C  ((NSq+T64-1)/T64) // 13 center tiles (last partial)
#define NSPL  4              // j-range splits (grid 784)
#define LDP   34             // LDS row stride (even -> 16B-aligned double2)

__device__ __constant__ int c_spl[NSPL + 1] = {0, 13, 25, 37, 49};

typedef unsigned int   u32;
typedef unsigned long long u64;

static __device__ __forceinline__ void atomicMaxPosD(double* p, double v) {
    atomicMax((u64*)p, (u64)__double_as_longlong(v));
}
static __device__ __forceinline__ int clampTok(int t) {
    return min(max(t, 0), Nq - 1);
}

// sorted-ascending insert into 5-list (static indices after unroll)
static __device__ __forceinline__ void ins5(double* a, double v) {
    if (v < a[KNN - 1]) {
        a[KNN - 1] = v;
        #pragma unroll
        for (int m = KNN - 1; m > 0; m--)
            if (a[m] < a[m - 1]) { double t = a[m]; a[m] = a[m - 1]; a[m - 1] = t; }
    }
}
// compare-exchange (branch-free, static)
static __device__ __forceinline__ void cex(double& a, double& b) {
    double lo = fmin(a, b), hi = fmax(a, b); a = lo; b = hi;
}
// merge two ascending 5-lists, keep 5 smallest ascending.
// STATIC INDICES ONLY (SROA -> VGPRs; dynamic idx caused 338 MB spill, R7/R8).
static __device__ __forceinline__ void merge5(double* a, const double* p) {
    double t0 = fmin(a[0], p[4]);
    double t1 = fmin(a[1], p[3]);
    double t2 = fmin(a[2], p[2]);
    double t3 = fmin(a[3], p[1]);
    double t4 = fmin(a[4], p[0]);
    cex(t0, t1); cex(t1, t2); cex(t2, t3); cex(t3, t4);
    cex(t0, t1); cex(t1, t2); cex(t2, t3);
    cex(t0, t1); cex(t1, t2);
    cex(t0, t1);
    a[0] = t0; a[1] = t1; a[2] = t2; a[3] = t3; a[4] = t4;
}

// ---- jax threefry2x32 noise: uniform(key(42), (4,3136)) -------------------
static __device__ __forceinline__ u32 rotl32(u32 x, int d) { return (x << d) | (x >> (32 - d)); }
static __device__ __forceinline__ float tf_uniform(int t) {
    const u32 k0 = 0u, k1 = 42u;
    const u32 ks2 = k0 ^ k1 ^ 0x1BD11BDAu;
    u32 ks[3] = { k0, k1, ks2 };
    bool lo = (t < 6272);
    u32 cx0 = lo ? (u32)t : (u32)(t - 6272);
    u32 cx1 = lo ? (u32)(t + 6272) : (u32)t;
    u32 x0 = cx0 + ks[0];
    u32 x1 = cx1 + ks[1];
    const int R0[4] = {13, 15, 26, 6};
    const int R1[4] = {17, 29, 16, 24};
    #pragma unroll
    for (int i = 0; i < 5; i++) {
        const int* rot = (i % 2 == 0) ? R0 : R1;
        #pragma unroll
        for (int r = 0; r < 4; r++) { x0 += x1; x1 = rotl32(x1, rot[r]); x1 ^= x0; }
        x0 += ks[(i + 1) % 3];
        x1 += ks[(i + 2) % 3] + (u32)(i + 1);
    }
    u32 bits = lo ? x0 : x1;
    u32 fb = (bits >> 9) | 0x3f800000u;
    float f; __builtin_memcpy(&f, &fb, 4);
    return f - 1.0f;
}

// ---- grid index: clip(loc,-1,1)*0.5+0.5 -> round-half-even ----------------
static __device__ __forceinline__ int gridIndex(float lx, float ly, int Wd, int Hd) {
    double x = fmin(fmax((double)lx, -1.0), 1.0) * 0.5 + 0.5;
    double y = fmin(fmax((double)ly, -1.0), 1.0) * 0.5 + 0.5;
    int ix = (int)rint(x * (double)(Wd - 1)); ix = min(max(ix, 0), Wd - 1);
    int iy = (int)rint(y * (double)(Hd - 1)); iy = min(max(iy, 0), Hd - 1);
    return iy * Wd + ix;
}

// ---------------------------------------------------------------------------
__global__ void ctm_fallback(float* out, int n) {
    int t = blockIdx.x * blockDim.x + threadIdx.x;
    if (t < n) out[t] = 0.0f;
}

__global__ void ctm_prep(const float* __restrict__ loc, const int* __restrict__ idx_agg,
                         const float* __restrict__ aggw,
                         int* cell56, int* cell28, int* cnt56, double* allwtok) {
    int t = blockIdx.x * blockDim.x + threadIdx.x;
    if (t >= BNq) return;
    int b = t / Nq;
    float lx = loc[2 * t], ly = loc[2 * t + 1];
    int c56 = gridIndex(lx, ly, Wq, Hq);
    int c28 = gridIndex(lx, ly, WOq, HOq);
    cell56[t] = c56; cell28[t] = c28;
    atomicAdd(&cnt56[b * HWq + c56], 1);
    int tok = clampTok(idx_agg[t]);
    atomicAdd(&allwtok[b * Nq + tok], (double)aggw[t]);
}

// t2m, (point,channel)-parallel: one coalesced f64 atomic per thread into the
// channel-contiguous transposed map xmap56T[b][cell][c].
__global__ void ctm_t2m(const float* __restrict__ x, const int* __restrict__ idx_agg,
                        const int* __restrict__ cell56, const int* __restrict__ cnt56,
                        double* xmap56T) {
    int id = blockIdx.x * blockDim.x + threadIdx.x;
    if (id >= BNq * Cq) return;
    int t = id / Cq, c = id - t * Cq;
    int b = t / Nq;
    int cell = cell56[t];
    double v = 1.0 / ((double)cnt56[b * HWq + cell] + 1e-6);
    double xv = (double)x[(size_t)(b * Nq + clampTok(idx_agg[t])) * Cq + c];
    atomicAdd(&xmap56T[((size_t)b * HWq + cell) * Cq + c], xv * v);
}

// one-time weight transpose: wT[(ci*9+tap)*C2q+co] = w[co*Cq*9 + ci*9 + tap]
// -> conv's weight loads become lane-coalesced (co fastest).
__global__ void ctm_wt(const float* __restrict__ w, float* wT) {
    int id = blockIdx.x * blockDim.x + threadIdx.x;
    if (id >= C2q * Cq * 9) return;
    int co = id & (C2q - 1);
    int rem = id >> 7;
    int tap = rem % 9;
    int ci = rem / 9;
    wT[id] = w[(size_t)co * Cq * 9 + ci * 9 + tap];
}

// conv 3x3 stride2, v2: block = 2 cells x 128 co. Input taps staged in LDS
// (coalesced, OOB -> 0.0; the R14 version did 576 serialized global
// broadcasts per thread -> 612 us at 3% VALUBusy). Weight reads from wT are
// lane-coalesced and L2-resident. Accumulation order ci,ky,kx ascending with
// +0.0 at OOB taps -- bit-neutral vs the skip version.
__global__ __launch_bounds__(256)
void ctm_conv(const double* __restrict__ xmap56T, const float* __restrict__ wT,
              const float* __restrict__ bias, double* xmap28T) {
    __shared__ double sIn[2][9][Cq];
    int blk = blockIdx.x;
    int b  = blk & (Bq - 1);
    int cp = blk >> 2;              // cell pair index, 0..391
    int tid = threadIdx.x;
    int co = tid & (C2q - 1);
    int cl = tid >> 7;              // 0 or 1
    const double* xb = xmap56T + (size_t)b * HWq * Cq;
    for (int idx = tid; idx < 2 * 9 * Cq; idx += 256) {
        int cell_l = idx / (9 * Cq);
        int rem = idx - cell_l * (9 * Cq);
        int tap = rem >> 6;
        int ci  = rem & 63;
        int cell = 2 * cp + cell_l;
        int ox = cell % WOq, oy = cell / WOq;
        int ky = tap / 3, kx = tap - ky * 3;
        int iy = 2 * oy + ky - 1, ix = 2 * ox + kx - 1;
        double v = 0.0;
        if (iy >= 0 && iy < Hq && ix >= 0 && ix < Wq)
            v = xb[(size_t)(iy * Wq + ix) * Cq + ci];
        sIn[cell_l][tap][ci] = v;
    }
    __syncthreads();
    double acc = (double)bias[co];
    for (int ci = 0; ci < Cq; ci++) {
        #pragma unroll
        for (int tap = 0; tap < 9; tap++)
            acc += sIn[cl][tap][ci] * (double)wT[(size_t)(ci * 9 + tap) * C2q + co];
    }
    int cell = 2 * cp + cl;
    xmap28T[((size_t)b * HWOq + cell) * C2q + co] = acc;
}

// m2t, (point,channel)-parallel: coalesced reads from xmap28T, one coalesced
// f64 atomic per thread into xt[tok][c].
__global__ void ctm_m2t(const double* __restrict__ xmap28T, const float* __restrict__ aggw,
                        const int* __restrict__ idx_agg, const int* __restrict__ cell28,
                        const double* __restrict__ allwtok, double* xt) {
    int id = blockIdx.x * blockDim.x + threadIdx.x;
    if (id >= BNq * C2q) return;
    int t = id / C2q, c = id - t * C2q;
    int b = t / Nq;
    int tok = clampTok(idx_agg[t]);
    double v = (double)aggw[t] / (allwtok[b * Nq + tok] + 1e-6);
    double f = xmap28T[((size_t)b * HWOq + cell28[t]) * C2q + c];
    atomicAdd(&xt[(size_t)(b * Nq + tok) * C2q + c], f * v);
}

__global__ __launch_bounds__(C2q)
void ctm_finalize(double* xt, const float* __restrict__ x, const float* __restrict__ skipw,
                  const float* __restrict__ lng, const float* __restrict__ lnb,
                  const float* __restrict__ confw, const float* __restrict__ confb,
                  double* x2o, double* weightv) {
    int bn = blockIdx.x; int c = threadIdx.x;
    double* row = xt + (size_t)bn * C2q;
    const float* xr = x + (size_t)bn * Cq;
    double acc = row[c];
    const float* sw = skipw + c * Cq;
    #pragma unroll 16
    for (int k = 0; k < Cq; k++) acc += (double)xr[k] * (double)sw[k];
    __shared__ double red[C2q];
    __shared__ double stat[2];
    red[c] = acc; __syncthreads();
    for (int off = C2q / 2; off > 0; off >>= 1) { if (c < off) red[c] += red[c + off]; __syncthreads(); }
    if (c == 0) stat[0] = red[0] * (1.0 / C2q);
    __syncthreads();
    double mu = stat[0];
    double d = acc - mu;
    red[c] = d * d; __syncthreads();
    for (int off = C2q / 2; off > 0; off >>= 1) { if (c < off) red[c] += red[c + off]; __syncthreads(); }
    if (c == 0) stat[1] = red[0] * (1.0 / C2q);
    __syncthreads();
    double var = stat[1];
    double v = d / sqrt(var + 1e-5) * (double)lng[c] + (double)lnb[c];
    row[c] = v;
    red[c] = v * v; __syncthreads();
    for (int off = C2q / 2; off > 0; off >>= 1) { if (c < off) red[c] += red[c + off]; __syncthreads(); }
    if (c == 0) x2o[bn] = red[0];
    __syncthreads();
    red[c] = v * (double)confw[c]; __syncthreads();
    for (int off = C2q / 2; off > 0; off >>= 1) { if (c < off) red[c] += red[c + off]; __syncthreads(); }
    if (c == 0) weightv[bn] = exp(red[0] + (double)confb[0]);
}

// ---------------------------------------------------------------------------
// Distance kernels v2.5: (256,2) = VGPR 84, no spill (R10-R12 evidence) plus
// XCD-aware block swizzle: batch b is the FASTEST block index (per-XCD L2
// working set 3.2 MB < 4 MB). Bit-identical arithmetic (c ascending per pair).
// ---------------------------------------------------------------------------

// pass1: per row i -> 5 smallest d2 + row max d2 (partial per j-split)
__global__ __launch_bounds__(256, 2)
void ctm_pass1(const double* __restrict__ xt, const double* __restrict__ x2,
               double* pbest, double* pmax) {
    __shared__ double sA[T64][LDP];
    __shared__ double sB[T64][LDP];
    __shared__ double sx2j[T64];
    int blk = blockIdx.x;
    int b  = blk & (Bq - 1);
    int s  = (blk >> 2) & (NSPL - 1);
    int it = blk >> 4;
    int tid = threadIdx.x, tx = tid & 15, ty = tid >> 4;
    const double* xtb = xt + (size_t)b * Nq * C2q;
    const double* x2b = x2 + (size_t)b * Nq;
    int i0 = it * T64;
    double x2i[4];
    #pragma unroll
    for (int r = 0; r < 4; r++) x2i[r] = x2b[i0 + ty + 16 * r];
    double best[4][KNN]; double mx[4];
    #pragma unroll
    for (int r = 0; r < 4; r++) {
        mx[r] = -DBL_MAX;
        #pragma unroll
        for (int k = 0; k < KNN; k++) best[r][k] = DBL_MAX;
    }
    int jt_beg = c_spl[s], jt_end = c_spl[s + 1];
    for (int jt = jt_beg; jt < jt_end; jt++) {
        int j0 = jt * T64;
        double acc[4][4];
        #pragma unroll
        for (int r = 0; r < 4; r++)
            #pragma unroll
            for (int q = 0; q < 4; q++) acc[r][q] = 0.0;
        for (int kc = 0; kc < 4; kc++) {
            __syncthreads();
            for (int idx = tid; idx < T64 * KC; idx += 256) {
                int r = idx >> 5, c = idx & 31;
                sA[r][c] = xtb[(size_t)(i0 + r) * C2q + kc * KC + c];
                sB[r][c] = xtb[(size_t)(j0 + r) * C2q + kc * KC + c];
            }
            if (kc == 0 && tid < T64) sx2j[tid] = x2b[j0 + tid];
            __syncthreads();
            #pragma unroll 4
            for (int cc = 0; cc < KC; cc += 2) {
                double2 xi[4], xj[4];
                #pragma unroll
                for (int r = 0; r < 4; r++) xi[r] = *(const double2*)&sA[ty + 16 * r][cc];
                #pragma unroll
                for (int q = 0; q < 4; q++) xj[q] = *(const double2*)&sB[tx + 16 * q][cc];
                #pragma unroll
                for (int r = 0; r < 4; r++)
                    #pragma unroll
                    for (int q = 0; q < 4; q++) acc[r][q] += xi[r].x * xj[q].x;
                #pragma unroll
                for (int r = 0; r < 4; r++)
                    #pragma unroll
                    for (int q = 0; q < 4; q++) acc[r][q] += xi[r].y * xj[q].y;
            }
        }
        #pragma unroll
        for (int r = 0; r < 4; r++)
            #pragma unroll
            for (int q = 0; q < 4; q++) {
                double d2 = x2i[r] + sx2j[tx + 16 * q] - 2.0 * acc[r][q];
                mx[r] = fmax(mx[r], d2);
                ins5(best[r], d2);
            }
    }
    for (int m = 1; m <= 8; m <<= 1) {
        #pragma unroll
        for (int r = 0; r < 4; r++) {
            double p[KNN];
            #pragma unroll
            for (int k = 0; k < KNN; k++) p[k] = __shfl_xor(best[r][k], m);
            mx[r] = fmax(mx[r], __shfl_xor(mx[r], m));
            merge5(best[r], p);
        }
    }
    if (tx == 0) {
        #pragma unroll
        for (int r = 0; r < 4; r++) {
            int gi = b * Nq + i0 + ty + 16 * r;
            size_t base = ((size_t)s * BNq + gi) * KNN;
            #pragma unroll
            for (int k = 0; k < KNN; k++) pbest[base + k] = best[r][k];
            pmax[(size_t)s * BNq + gi] = mx[r];
        }
    }
}

// merge pass1 partials -> density + rowmax2
__global__ void ctm_merge1(const double* __restrict__ pbest, const double* __restrict__ pmax,
                           double* density, double* rowmax2) {
    int t = blockIdx.x * blockDim.x + threadIdx.x;
    if (t >= BNq) return;
    double a[KNN];
    #pragma unroll
    for (int k = 0; k < KNN; k++) a[k] = pbest[(size_t)t * KNN + k];
    double mxv = pmax[t];
    #pragma unroll
    for (int s = 1; s < NSPL; s++) {
        double p[KNN];
        #pragma unroll
        for (int k = 0; k < KNN; k++) p[k] = pbest[((size_t)s * BNq + t) * KNN + k];
        merge5(a, p);
        mxv = fmax(mxv, pmax[(size_t)s * BNq + t]);
    }
    double sum = 0.0;
    #pragma unroll
    for (int k = 0; k < KNN; k++) sum += fmax(a[k], 0.0);
    density[t] = exp(-sum / (double)(C2q * KNN)) + (double)(tf_uniform(t) * 1e-6f);
    rowmax2[t] = mxv;
}

__global__ __launch_bounds__(256)
void ctm_rowmax(const double* __restrict__ rowmax2, double* maxd2) {
    int b = blockIdx.x, tid = threadIdx.x;
    double m = -DBL_MAX;
    for (int i = tid; i < Nq; i += 256) m = fmax(m, rowmax2[b * Nq + i]);
    __shared__ double sm[256];
    sm[tid] = m; __syncthreads();
    for (int off = 128; off > 0; off >>= 1) { if (tid < off) sm[tid] = fmax(sm[tid], sm[tid + off]); __syncthreads(); }
    if (tid == 0) maxd2[b] = sm[0];
}

// pass2: min d2 over higher-density j (partial per j-split)
__global__ __launch_bounds__(256, 2)
void ctm_pass2(const double* __restrict__ xt, const double* __restrict__ x2,
               const double* __restrict__ density, double* pmin) {
    __shared__ double sA[T64][LDP];
    __shared__ double sB[T64][LDP];
    __shared__ double sx2j[T64];
    __shared__ double sdj[T64];
    int blk = blockIdx.x;
    int b  = blk & (Bq - 1);
    int s  = (blk >> 2) & (NSPL - 1);
    int it = blk >> 4;
    int tid = threadIdx.x, tx = tid & 15, ty = tid >> 4;
    const double* xtb = xt + (size_t)b * Nq * C2q;
    const double* x2b = x2 + (size_t)b * Nq;
    const double* db  = density + (size_t)b * Nq;
    int i0 = it * T64;
    double x2i[4], di[4], mn[4];
    #pragma unroll
    for (int r = 0; r < 4; r++) {
        x2i[r] = x2b[i0 + ty + 16 * r];
        di[r]  = db[i0 + ty + 16 * r];
        mn[r]  = DBL_MAX;
    }
    int jt_beg = c_spl[s], jt_end = c_spl[s + 1];
    for (int jt = jt_beg; jt < jt_end; jt++) {
        int j0 = jt * T64;
        double acc[4][4];
        #pragma unroll
        for (int r = 0; r < 4; r++)
            #pragma unroll
            for (int q = 0; q < 4; q++) acc[r][q] = 0.0;
        for (int kc = 0; kc < 4; kc++) {
            __syncthreads();
            for (int idx = tid; idx < T64 * KC; idx += 256) {
                int r = idx >> 5, c = idx & 31;
                sA[r][c] = xtb[(size_t)(i0 + r) * C2q + kc * KC + c];
                sB[r][c] = xtb[(size_t)(j0 + r) * C2q + kc * KC + c];
            }
            if (kc == 0 && tid < T64) { sx2j[tid] = x2b[j0 + tid]; sdj[tid] = db[j0 + tid]; }
            __syncthreads();
            #pragma unroll 4
            for (int cc = 0; cc < KC; cc += 2) {
                double2 xi[4], xj[4];
                #pragma unroll
                for (int r = 0; r < 4; r++) xi[r] = *(const double2*)&sA[ty + 16 * r][cc];
                #pragma unroll
                for (int q = 0; q < 4; q++) xj[q] = *(const double2*)&sB[tx + 16 * q][cc];
                #pragma unroll
                for (int r = 0; r < 4; r++)
                    #pragma unroll
                    for (int q = 0; q < 4; q++) acc[r][q] += xi[r].x * xj[q].x;
                #pragma unroll
                for (int r = 0; r < 4; r++)
                    #pragma unroll
                    for (int q = 0; q < 4; q++) acc[r][q] += xi[r].y * xj[q].y;
            }
        }
        #pragma unroll
        for (int r = 0; r < 4; r++)
            #pragma unroll
            for (int q = 0; q < 4; q++) {
                double d2 = x2i[r] + sx2j[tx + 16 * q] - 2.0 * acc[r][q];
                if (sdj[tx + 16 * q] > di[r]) mn[r] = fmin(mn[r], d2);
            }
    }
    for (int m = 1; m <= 8; m <<= 1) {
        #pragma unroll
        for (int r = 0; r < 4; r++) mn[r] = fmin(mn[r], __shfl_xor(mn[r], m));
    }
    if (tx == 0) {
        #pragma unroll
        for (int r = 0; r < 4; r++) {
            int gi = b * Nq + i0 + ty + 16 * r;
            pmin[(size_t)s * BNq + gi] = mn[r];
        }
    }
}

// merge pass2 partials -> score
__global__ void ctm_merge2(const double* __restrict__ pmin, const double* __restrict__ maxd2,
                           const double* __restrict__ density, double* score) {
    int t = blockIdx.x * blockDim.x + threadIdx.x;
    if (t >= BNq) return;
    int b = t / Nq;
    double m = pmin[t];
    #pragma unroll
    for (int s = 1; s < NSPL; s++) m = fmin(m, pmin[(size_t)s * BNq + t]);
    double mm = fmin(maxd2[b], m);
    score[t] = sqrt(fmax(mm, 0.0)) / sqrt((double)C2q) * density[t];
}

// top-784 with jax.lax.top_k semantics: total order (score desc, idx asc).
__global__ __launch_bounds__(1024)
void ctm_sort(const double* __restrict__ score, int* index_down) {
    __shared__ double s[4096];
    __shared__ int   si[4096];
    int b = blockIdx.x, tid = threadIdx.x;
    for (int i = tid; i < 4096; i += 1024) {
        if (i < Nq) {
            double v = score[b * Nq + i];
            s[i] = isnan(v) ? -DBL_MAX : v;
            si[i] = i;
        } else { s[i] = -DBL_MAX; si[i] = 0x7fffffff; }
    }
    __syncthreads();
    for (int k = 2; k <= 4096; k <<= 1) {
        for (int j = k >> 1; j > 0; j >>= 1) {
            for (int i = tid; i < 4096; i += 1024) {
                int ixj = i ^ j;
                if (ixj > i) {
                    double s1 = s[i], s2 = s[ixj];
                    int i1 = si[i], i2 = si[ixj];
                    bool before_ij = (s1 > s2) || (s1 == s2 && i1 < i2);
                    bool before_ji = (s2 > s1) || (s2 == s1 && i2 < i1);
                    bool doswap = ((i & k) == 0) ? before_ji : before_ij;
                    if (doswap) { s[i] = s2; s[ixj] = s1; si[i] = i2; si[ixj] = i1; }
                }
            }
            __syncthreads();
        }
    }
    for (int t = tid; t < NSq; t += 1024) {
        int v = si[t];
        index_down[b * NSq + t] = ((unsigned)v < (unsigned)Nq) ? v : 0;
    }
}

// assign: argmin over 784 centers, tie-break smallest sc (lexicographic d,sc)
__global__ __launch_bounds__(256, 2)
void ctm_assign(const double* __restrict__ xt, const double* __restrict__ x2,
                const int* __restrict__ index_down, int* idx_cluster) {
    __shared__ double sA[T64][LDP];
    __shared__ double sB[T64][LDP];
    __shared__ double sx2c[T64];
    __shared__ int    sidx[T64];
    int blk = blockIdx.x;
    int b  = blk & (Bq - 1);
    int it = blk >> 2;
    int tid = threadIdx.x, tx = tid & 15, ty = tid >> 4;
    const double* xtb = xt + (size_t)b * Nq * C2q;
    const double* x2b = x2 + (size_t)b * Nq;
    int i0 = it * T64;
    double x2i[4], bd[4];
    int bs[4];
    #pragma unroll
    for (int r = 0; r < 4; r++) { x2i[r] = x2b[i0 + ty + 16 * r]; bd[r] = DBL_MAX; bs[r] = NSq - 1; }
    for (int jt = 0; jt < NT_C; jt++) {
        int j0 = jt * T64;
        __syncthreads();
        if (tid < T64) {
            int j = index_down[b * NSq + min(j0 + tid, NSq - 1)];
            sidx[tid] = j;
            sx2c[tid] = x2b[j];
        }
        __syncthreads();
        double acc[4][4];
        #pragma unroll
        for (int r = 0; r < 4; r++)
            #pragma unroll
            for (int q = 0; q < 4; q++) acc[r][q] = 0.0;
        for (int kc = 0; kc < 4; kc++) {
            if (kc) __syncthreads();
            for (int idx = tid; idx < T64 * KC; idx += 256) {
                int r = idx >> 5, c = idx & 31;
                sA[r][c] = xtb[(size_t)(i0 + r) * C2q + kc * KC + c];
                sB[r][c] = xtb[(size_t)sidx[r] * C2q + kc * KC + c];
            }
            __syncthreads();
            #pragma unroll 4
            for (int cc = 0; cc < KC; cc += 2) {
                double2 xi[4], xj[4];
                #pragma unroll
                for (int r = 0; r < 4; r++) xi[r] = *(const double2*)&sA[ty + 16 * r][cc];
                #pragma unroll
                for (int q = 0; q < 4; q++) xj[q] = *(const double2*)&sB[tx + 16 * q][cc];
                #pragma unroll
                for (int r = 0; r < 4; r++)
                    #pragma unroll
                    for (int q = 0; q < 4; q++) acc[r][q] += xi[r].x * xj[q].x;
                #pragma unroll
                for (int r = 0; r < 4; r++)
                    #pragma unroll
                    for (int q = 0; q < 4; q++) acc[r][q] += xi[r].y * xj[q].y;
            }
        }
        #pragma unroll
        for (int r = 0; r < 4; r++)
            #pragma unroll
            for (int q = 0; q < 4; q++) {
                int sc = j0 + tx + 16 * q;
                double d = fmax(x2i[r] + sx2c[tx + 16 * q] - 2.0 * acc[r][q], 0.0);
                if (sc < NSq && (d < bd[r] || (d == bd[r] && sc < bs[r]))) { bd[r] = d; bs[r] = sc; }
            }
    }
    for (int m = 1; m <= 8; m <<= 1) {
        #pragma unroll
        for (int r = 0; r < 4; r++) {
            double pd = __shfl_xor(bd[r], m);
            int    ps = __shfl_xor(bs[r], m);
            if (pd < bd[r] || (pd == bd[r] && ps < bs[r])) { bd[r] = pd; bs[r] = ps; }
        }
    }
    if (tx == 0) {
        #pragma unroll
        for (int r = 0; r < 4; r++) idx_cluster[b * Nq + i0 + ty + 16 * r] = bs[r];
    }
}

__global__ void ctm_override(const int* __restrict__ index_down, int* idx_cluster) {
    int t = blockIdx.x * blockDim.x + threadIdx.x;
    if (t >= Bq * NSq) return;
    int b = t / NSq, sc = t - b * NSq;
    int j = index_down[t];
    if ((unsigned)j < (unsigned)Nq) idx_cluster[b * Nq + j] = sc;
}

__global__ void ctm_zeromerged(double* xmerged) {
    int t = blockIdx.x * blockDim.x + threadIdx.x;
    if (t < Bq * NSq * C2q) xmerged[t] = 0.0;
}

__global__ void ctm_merge_w(const int* __restrict__ idx_cluster, const double* __restrict__ weightv,
                            double* allwc) {
    int t = blockIdx.x * blockDim.x + threadIdx.x;
    if (t >= BNq) return;
    int b = t / Nq;
    int sc = min(max(idx_cluster[t], 0), NSq - 1);
    atomicAdd(&allwc[b * NSq + sc], weightv[t]);
}

// merge_x, (point,channel)-parallel: one coalesced atomic per thread.
__global__ void ctm_merge_x(const int* __restrict__ idx_cluster, const double* __restrict__ weightv,
                            const double* __restrict__ allwc, const double* __restrict__ xt,
                            double* nw, double* xmerged) {
    int id = blockIdx.x * blockDim.x + threadIdx.x;
    if (id >= BNq * C2q) return;
    int t = id / C2q, c = id - t * C2q;
    int b = t / Nq;
    int sc = min(max(idx_cluster[t], 0), NSq - 1);
    double nv = weightv[t] / (allwc[b * NSq + sc] + 1e-6);
    if (c == 0) nw[t] = nv;
    atomicAdd(&xmerged[((size_t)(b * NSq + sc)) * C2q + c], xt[(size_t)t * C2q + c] * nv);
}

__global__ void ctm_out0(const double* __restrict__ xmerged, float* out) {
    int t = blockIdx.x * blockDim.x + threadIdx.x;
    if (t >= Bq * NSq * C2q) return;
    out[t] = (float)xmerged[t];
}

__global__ void ctm_out12(const int* __restrict__ idx_agg, const int* __restrict__ idx_cluster,
                          const double* __restrict__ nw, const float* __restrict__ aggw,
                          float* out1, double* awd, double* maxawd) {
    int t = blockIdx.x * blockDim.x + threadIdx.x;
    if (t >= BNq) return;
    int b = t / Nq;
    int tok = clampTok(idx_agg[t]);
    int sc = idx_cluster[b * Nq + tok];
    out1[t] = (float)sc;
    double a = (double)aggw[t] * nw[b * Nq + tok];
    awd[t] = a;
    atomicMaxPosD(&maxawd[b], a);
}

__global__ void ctm_out2(const double* __restrict__ awd, const double* __restrict__ maxawd, float* out2) {
    int t = blockIdx.x * blockDim.x + threadIdx.x;
    if (t >= BNq) return;
    int b = t / Nq;
    out2[t] = (float)(awd[t] / maxawd[b]);
}

// ---------------------------------------------------------------------------
extern "C" void kernel_launch(void* const* d_in, const int* in_sizes, int n_in,
                              void* d_out, int out_size, void* d_ws, size_t ws_size,
                              hipStream_t stream) {
    const float* x     = (const float*)d_in[0];
    const float* loc   = (const float*)d_in[1];
    const int*   idxag = (const int*)  d_in[2];
    const float* aggw  = (const float*)d_in[3];
    const float* convw = (const float*)d_in[4];
    const float* convb = (const float*)d_in[5];
    const float* skipw = (const float*)d_in[6];
    const float* lng   = (const float*)d_in[7];
    const float* lnb   = (const float*)d_in[8];
    const float* confw = (const float*)d_in[9];
    const float* confb = (const float*)d_in[10];
    (void)in_sizes; (void)n_in;

    char* w = (char*)d_ws;
    size_t off = 0;
    auto alloc = [&](size_t bytes) -> void* {
        void* p = w + off; off = (off + bytes + 255) & ~(size_t)255; return p;
    };

    // ---- zero-initialized region (one memset) ----
    int*    cnt56   = (int*)   alloc((size_t)BNq * 4);
    double* allwtok = (double*)alloc((size_t)BNq * 8);
    double* xt      = (double*)alloc((size_t)BNq * C2q * 8);
    double* arena   = (double*)alloc((size_t)Bq * HWq * Cq * 8);   // xmap56T, later xmerged
    double* allwc   = (double*)alloc((size_t)Bq * NSq * 8);
    double* maxawd  = (double*)alloc((size_t)Bq * 8);
    size_t zero_bytes = off;
    // ---- non-zero region ----
    int*    cell56   = (int*)   alloc((size_t)BNq * 4);
    int*    cell28   = (int*)   alloc((size_t)BNq * 4);
    double* xmap28T  = (double*)alloc((size_t)Bq * HWOq * C2q * 8);
    float*  wT       = (float*) alloc((size_t)C2q * Cq * 9 * 4);
    double* x2       = (double*)alloc((size_t)BNq * 8);
    double* density  = (double*)alloc((size_t)BNq * 8);
    double* rowmax2  = (double*)alloc((size_t)BNq * 8);
    double* maxd2    = (double*)alloc((size_t)Bq * 8);
    double* score    = (double*)alloc((size_t)BNq * 8);
    int*    indexdn  = (int*)   alloc((size_t)Bq * NSq * 4);
    int*    idxclu   = (int*)   alloc((size_t)BNq * 4);
    double* nw       = (double*)alloc((size_t)BNq * 8);
    double* weightv  = (double*)alloc((size_t)BNq * 8);
    double* awd      = (double*)alloc((size_t)BNq * 8);
    double* pbest    = (double*)alloc((size_t)NSPL * BNq * KNN * 8);
    double* pmax     = (double*)alloc((size_t)NSPL * BNq * 8);
    double* pmin     = (double*)alloc((size_t)NSPL * BNq * 8);
    size_t required = off;

    const int tb = 256;
    float* out = (float*)d_out;

    if (ws_size < required) {
        ctm_fallback<<<(out_size + tb - 1) / tb, tb, 0, stream>>>(out, out_size);
        return;
    }

    double* xmap56T = arena;
    double* xmerged = arena;   // reused after conv; re-zeroed below

    hipMemsetAsync(d_ws, 0, zero_bytes, stream);

    ctm_prep<<<(BNq + tb - 1) / tb, tb, 0, stream>>>(loc, idxag, aggw, cell56, cell28, cnt56, allwtok);
    ctm_wt<<<((C2q * Cq * 9) + tb - 1) / tb, tb, 0, stream>>>(convw, wT);
    ctm_t2m<<<((BNq * Cq) + tb - 1) / tb, tb, 0, stream>>>(x, idxag, cell56, cnt56, xmap56T);
    ctm_conv<<<Bq * (HWOq / 2), 256, 0, stream>>>(xmap56T, wT, convb, xmap28T);
    ctm_m2t<<<((BNq * C2q) + tb - 1) / tb, tb, 0, stream>>>(xmap28T, aggw, idxag, cell28, allwtok, xt);
    ctm_finalize<<<BNq, C2q, 0, stream>>>(xt, x, skipw, lng, lnb, confw, confb, x2, weightv);
    ctm_pass1<<<Bq * NIT64 * NSPL, 256, 0, stream>>>(xt, x2, pbest, pmax);
    ctm_merge1<<<(BNq + tb - 1) / tb, tb, 0, stream>>>(pbest, pmax, density, rowmax2);
    ctm_rowmax<<<Bq, 256, 0, stream>>>(rowmax2, maxd2);
    ctm_pass2<<<Bq * NIT64 * NSPL, 256, 0, stream>>>(xt, x2, density, pmin);
    ctm_merge2<<<(BNq + tb - 1) / tb, tb, 0, stream>>>(pmin, maxd2, density, score);
    ctm_sort<<<Bq, 1024, 0, stream>>>(score, indexdn);
    ctm_assign<<<Bq * NIT64, 256, 0, stream>>>(xt, x2, indexdn, idxclu);
    ctm_override<<<((Bq * NSq) + tb - 1) / tb, tb, 0, stream>>>(indexdn, idxclu);
    ctm_zeromerged<<<((Bq * NSq * C2q) + tb - 1) / tb, tb, 0, stream>>>(xmerged);
    ctm_merge_w<<<(BNq + tb - 1) / tb, tb, 0, stream>>>(idxclu, weightv, allwc);
    ctm_merge_x<<<((BNq * C2q) + tb - 1) / tb, tb, 0, stream>>>(idxclu, weightv, allwc, xt, nw, xmerged);

    ctm_out0<<<((Bq * NSq * C2q) + tb - 1) / tb, tb, 0, stream>>>(xmerged, out);
    ctm_out12<<<(BNq + tb - 1) / tb, tb, 0, stream>>>(idxag, idxclu, nw, aggw,
                                                      out + (size_t)Bq * NSq * C2q, awd, maxawd);
    ctm_out2<<<(BNq + tb - 1) / tb, tb, 0, stream>>>(awd, maxawd,
                                                     out + (size_t)Bq * NSq * C2q + BNq);
}

// Round 16
// 1483.521 us; speedup vs baseline: 1.3934x; 1.0063x over previous
//
#include <hip/hip_runtime.h>
#include <math.h>
#include <float.h>

// Problem constants: B=4, N=3136, C=64, C2=128, H=W=56, stride2 -> 28x28,
// Ns = ceil(N*0.25) = 784, k = 5.  Inputs are float32/int32 per reference.
#define Bq   4
#define Nq   3136
#define Cq   64
#define C2q  128
#define Hq   56
#define Wq   56
#define HWq  (Hq*Wq)
#define HOq  28
#define WOq  28
#define HWOq (HOq*WOq)
#define NSq  784
#define KNN  5
#define BNq  (Bq*Nq)

#define T64   64             // i/j tile for distance kernels
#define KC    32             // K chunk
#define NIT64 (Nq/T64)       // 49 i-tiles (exact)
#define NT_C  ((NSq+T64-1)/T64) // 13 center tiles (last partial)
#define NSPL  8              // j-range splits (grid 1568 -> 4 resident blocks/CU)
#define NSPA  2              // assign center-range splits
#define LDP   34             // LDS row stride (even -> 16B-aligned double2)

__device__ __constant__ int c_spl[NSPL + 1]  = {0, 7, 13, 19, 25, 31, 37, 43, 49};
__device__ __constant__ int c_spla[NSPA + 1] = {0, 7, 13};

typedef unsigned int   u32;
typedef unsigned long long u64;

static __device__ __forceinline__ void atomicMaxPosD(double* p, double v) {
    // valid for non-negative doubles: bit pattern is order-isomorphic
    atomicMax((u64*)p, (u64)__double_as_longlong(v));
}
static __device__ __forceinline__ int clampTok(int t) {
    return min(max(t, 0), Nq - 1);
}

// sorted-ascending insert into 5-list (static indices after unroll)
static __device__ __forceinline__ void ins5(double* a, double v) {
    if (v < a[KNN - 1]) {
        a[KNN - 1] = v;
        #pragma unroll
        for (int m = KNN - 1; m > 0; m--)
            if (a[m] < a[m - 1]) { double t = a[m]; a[m] = a[m - 1]; a[m - 1] = t; }
    }
}
// compare-exchange (branch-free, static)
static __device__ __forceinline__ void cex(double& a, double& b) {
    double lo = fmin(a, b), hi = fmax(a, b); a = lo; b = hi;
}
// merge two ascending 5-lists, keep 5 smallest ascending.
// STATIC INDICES ONLY (SROA -> VGPRs; dynamic idx caused 338 MB spill, R7/R8).
static __device__ __forceinline__ void merge5(double* a, const double* p) {
    double t0 = fmin(a[0], p[4]);
    double t1 = fmin(a[1], p[3]);
    double t2 = fmin(a[2], p[2]);
    double t3 = fmin(a[3], p[1]);
    double t4 = fmin(a[4], p[0]);
    cex(t0, t1); cex(t1, t2); cex(t2, t3); cex(t3, t4);
    cex(t0, t1); cex(t1, t2); cex(t2, t3);
    cex(t0, t1); cex(t1, t2);
    cex(t0, t1);
    a[0] = t0; a[1] = t1; a[2] = t2; a[3] = t3; a[4] = t4;
}

// ---- jax threefry2x32 noise: uniform(key(42), (4,3136)) -------------------
static __device__ __forceinline__ u32 rotl32(u32 x, int d) { return (x << d) | (x >> (32 - d)); }
static __device__ __forceinline__ float tf_uniform(int t) {
    const u32 k0 = 0u, k1 = 42u;
    const u32 ks2 = k0 ^ k1 ^ 0x1BD11BDAu;
    u32 ks[3] = { k0, k1, ks2 };
    bool lo = (t < 6272);
    u32 cx0 = lo ? (u32)t : (u32)(t - 6272);
    u32 cx1 = lo ? (u32)(t + 6272) : (u32)t;
    u32 x0 = cx0 + ks[0];
    u32 x1 = cx1 + ks[1];
    const int R0[4] = {13, 15, 26, 6};
    const int R1[4] = {17, 29, 16, 24};
    #pragma unroll
    for (int i = 0; i < 5; i++) {
        const int* rot = (i % 2 == 0) ? R0 : R1;
        #pragma unroll
        for (int r = 0; r < 4; r++) { x0 += x1; x1 = rotl32(x1, rot[r]); x1 ^= x0; }
        x0 += ks[(i + 1) % 3];
        x1 += ks[(i + 2) % 3] + (u32)(i + 1);
    }
    u32 bits = lo ? x0 : x1;
    u32 fb = (bits >> 9) | 0x3f800000u;
    float f; __builtin_memcpy(&f, &fb, 4);
    return f - 1.0f;
}

// ---- grid index: clip(loc,-1,1)*0.5+0.5 -> round-half-even ----------------
static __device__ __forceinline__ int gridIndex(float lx, float ly, int Wd, int Hd) {
    double x = fmin(fmax((double)lx, -1.0), 1.0) * 0.5 + 0.5;
    double y = fmin(fmax((double)ly, -1.0), 1.0) * 0.5 + 0.5;
    int ix = (int)rint(x * (double)(Wd - 1)); ix = min(max(ix, 0), Wd - 1);
    int iy = (int)rint(y * (double)(Hd - 1)); iy = min(max(iy, 0), Hd - 1);
    return iy * Wd + ix;
}

// ---------------------------------------------------------------------------
__global__ void ctm_fallback(float* out, int n) {
    int t = blockIdx.x * blockDim.x + threadIdx.x;
    if (t < n) out[t] = 0.0f;
}

__global__ void ctm_prep(const float* __restrict__ loc, const int* __restrict__ idx_agg,
                         const float* __restrict__ aggw,
                         int* cell56, int* cell28, int* cnt56, double* allwtok) {
    int t = blockIdx.x * blockDim.x + threadIdx.x;
    if (t >= BNq) return;
    int b = t / Nq;
    float lx = loc[2 * t], ly = loc[2 * t + 1];
    int c56 = gridIndex(lx, ly, Wq, Hq);
    int c28 = gridIndex(lx, ly, WOq, HOq);
    cell56[t] = c56; cell28[t] = c28;
    atomicAdd(&cnt56[b * HWq + c56], 1);
    int tok = clampTok(idx_agg[t]);
    atomicAdd(&allwtok[b * Nq + tok], (double)aggw[t]);
}

// t2m, (point,channel)-parallel: one coalesced f64 atomic per thread into the
// channel-contiguous transposed map xmap56T[b][cell][c].
__global__ void ctm_t2m(const float* __restrict__ x, const int* __restrict__ idx_agg,
                        const int* __restrict__ cell56, const int* __restrict__ cnt56,
                        double* xmap56T) {
    int id = blockIdx.x * blockDim.x + threadIdx.x;
    if (id >= BNq * Cq) return;
    int t = id / Cq, c = id - t * Cq;
    int b = t / Nq;
    int cell = cell56[t];
    double v = 1.0 / ((double)cnt56[b * HWq + cell] + 1e-6);
    double xv = (double)x[(size_t)(b * Nq + clampTok(idx_agg[t])) * Cq + c];
    atomicAdd(&xmap56T[((size_t)b * HWq + cell) * Cq + c], xv * v);
}

// one-time weight transpose: wT[(ci*9+tap)*C2q+co] = w[co*Cq*9 + ci*9 + tap]
__global__ void ctm_wt(const float* __restrict__ w, float* wT) {
    int id = blockIdx.x * blockDim.x + threadIdx.x;
    if (id >= C2q * Cq * 9) return;
    int co = id & (C2q - 1);
    int rem = id >> 7;
    int tap = rem % 9;
    int ci = rem / 9;
    wT[id] = w[(size_t)co * Cq * 9 + ci * 9 + tap];
}

// conv 3x3 stride2: block = 2 cells x 128 co, input taps staged in LDS
// (OOB -> 0.0, bit-neutral), wT lane-coalesced.
__global__ __launch_bounds__(256)
void ctm_conv(const double* __restrict__ xmap56T, const float* __restrict__ wT,
              const float* __restrict__ bias, double* xmap28T) {
    __shared__ double sIn[2][9][Cq];
    int blk = blockIdx.x;
    int b  = blk & (Bq - 1);
    int cp = blk >> 2;              // cell pair index, 0..391
    int tid = threadIdx.x;
    int co = tid & (C2q - 1);
    int cl = tid >> 7;              // 0 or 1
    const double* xb = xmap56T + (size_t)b * HWq * Cq;
    for (int idx = tid; idx < 2 * 9 * Cq; idx += 256) {
        int cell_l = idx / (9 * Cq);
        int rem = idx - cell_l * (9 * Cq);
        int tap = rem >> 6;
        int ci  = rem & 63;
        int cell = 2 * cp + cell_l;
        int ox = cell % WOq, oy = cell / WOq;
        int ky = tap / 3, kx = tap - ky * 3;
        int iy = 2 * oy + ky - 1, ix = 2 * ox + kx - 1;
        double v = 0.0;
        if (iy >= 0 && iy < Hq && ix >= 0 && ix < Wq)
            v = xb[(size_t)(iy * Wq + ix) * Cq + ci];
        sIn[cell_l][tap][ci] = v;
    }
    __syncthreads();
    double acc = (double)bias[co];
    for (int ci = 0; ci < Cq; ci++) {
        #pragma unroll
        for (int tap = 0; tap < 9; tap++)
            acc += sIn[cl][tap][ci] * (double)wT[(size_t)(ci * 9 + tap) * C2q + co];
    }
    int cell = 2 * cp + cl;
    xmap28T[((size_t)b * HWOq + cell) * C2q + co] = acc;
}

// m2t, (point,channel)-parallel: coalesced.
__global__ void ctm_m2t(const double* __restrict__ xmap28T, const float* __restrict__ aggw,
                        const int* __restrict__ idx_agg, const int* __restrict__ cell28,
                        const double* __restrict__ allwtok, double* xt) {
    int id = blockIdx.x * blockDim.x + threadIdx.x;
    if (id >= BNq * C2q) return;
    int t = id / C2q, c = id - t * C2q;
    int b = t / Nq;
    int tok = clampTok(idx_agg[t]);
    double v = (double)aggw[t] / (allwtok[b * Nq + tok] + 1e-6);
    double f = xmap28T[((size_t)b * HWOq + cell28[t]) * C2q + c];
    atomicAdd(&xt[(size_t)(b * Nq + tok) * C2q + c], f * v);
}

__global__ __launch_bounds__(C2q)
void ctm_finalize(double* xt, const float* __restrict__ x, const float* __restrict__ skipw,
                  const float* __restrict__ lng, const float* __restrict__ lnb,
                  const float* __restrict__ confw, const float* __restrict__ confb,
                  double* x2o, double* weightv) {
    int bn = blockIdx.x; int c = threadIdx.x;
    double* row = xt + (size_t)bn * C2q;
    const float* xr = x + (size_t)bn * Cq;
    double acc = row[c];
    const float* sw = skipw + c * Cq;
    #pragma unroll 16
    for (int k = 0; k < Cq; k++) acc += (double)xr[k] * (double)sw[k];
    __shared__ double red[C2q];
    __shared__ double stat[2];
    red[c] = acc; __syncthreads();
    for (int off = C2q / 2; off > 0; off >>= 1) { if (c < off) red[c] += red[c + off]; __syncthreads(); }
    if (c == 0) stat[0] = red[0] * (1.0 / C2q);
    __syncthreads();
    double mu = stat[0];
    double d = acc - mu;
    red[c] = d * d; __syncthreads();
    for (int off = C2q / 2; off > 0; off >>= 1) { if (c < off) red[c] += red[c + off]; __syncthreads(); }
    if (c == 0) stat[1] = red[0] * (1.0 / C2q);
    __syncthreads();
    double var = stat[1];
    double v = d / sqrt(var + 1e-5) * (double)lng[c] + (double)lnb[c];
    row[c] = v;
    red[c] = v * v; __syncthreads();
    for (int off = C2q / 2; off > 0; off >>= 1) { if (c < off) red[c] += red[c + off]; __syncthreads(); }
    if (c == 0) x2o[bn] = red[0];
    __syncthreads();
    red[c] = v * (double)confw[c]; __syncthreads();
    for (int off = C2q / 2; off > 0; off >>= 1) { if (c < off) red[c] += red[c + off]; __syncthreads(); }
    if (c == 0) weightv[bn] = exp(red[0] + (double)confb[0]);
}

// ---------------------------------------------------------------------------
// Distance kernels v2.6: (256,2) no-spill config + XCD swizzle (b fastest)
// + NSPL=8 j-splits (grid 1568 -> 4 resident blocks/CU, 16 waves/CU to hide
// the LDS stream; R15 at NSPL=4 was 3.06 blocks/CU, 20% occupancy).
// Bit-identical arithmetic (c ascending per pair); partial knn/max/min merges
// are split-invariant.
// ---------------------------------------------------------------------------

// pass1: per row i -> 5 smallest d2 + row max d2 (partial per j-split)
__global__ __launch_bounds__(256, 2)
void ctm_pass1(const double* __restrict__ xt, const double* __restrict__ x2,
               double* pbest, double* pmax) {
    __shared__ double sA[T64][LDP];
    __shared__ double sB[T64][LDP];
    __shared__ double sx2j[T64];
    int blk = blockIdx.x;
    int b  = blk & (Bq - 1);
    int s  = (blk >> 2) & (NSPL - 1);
    int it = blk >> 5;
    int tid = threadIdx.x, tx = tid & 15, ty = tid >> 4;
    const double* xtb = xt + (size_t)b * Nq * C2q;
    const double* x2b = x2 + (size_t)b * Nq;
    int i0 = it * T64;
    double x2i[4];
    #pragma unroll
    for (int r = 0; r < 4; r++) x2i[r] = x2b[i0 + ty + 16 * r];
    double best[4][KNN]; double mx[4];
    #pragma unroll
    for (int r = 0; r < 4; r++) {
        mx[r] = -DBL_MAX;
        #pragma unroll
        for (int k = 0; k < KNN; k++) best[r][k] = DBL_MAX;
    }
    int jt_beg = c_spl[s], jt_end = c_spl[s + 1];
    for (int jt = jt_beg; jt < jt_end; jt++) {
        int j0 = jt * T64;
        double acc[4][4];
        #pragma unroll
        for (int r = 0; r < 4; r++)
            #pragma unroll
            for (int q = 0; q < 4; q++) acc[r][q] = 0.0;
        for (int kc = 0; kc < 4; kc++) {
            __syncthreads();
            for (int idx = tid; idx < T64 * KC; idx += 256) {
                int r = idx >> 5, c = idx & 31;
                sA[r][c] = xtb[(size_t)(i0 + r) * C2q + kc * KC + c];
                sB[r][c] = xtb[(size_t)(j0 + r) * C2q + kc * KC + c];
            }
            if (kc == 0 && tid < T64) sx2j[tid] = x2b[j0 + tid];
            __syncthreads();
            #pragma unroll 4
            for (int cc = 0; cc < KC; cc += 2) {
                double2 xi[4], xj[4];
                #pragma unroll
                for (int r = 0; r < 4; r++) xi[r] = *(const double2*)&sA[ty + 16 * r][cc];
                #pragma unroll
                for (int q = 0; q < 4; q++) xj[q] = *(const double2*)&sB[tx + 16 * q][cc];
                #pragma unroll
                for (int r = 0; r < 4; r++)
                    #pragma unroll
                    for (int q = 0; q < 4; q++) acc[r][q] += xi[r].x * xj[q].x;
                #pragma unroll
                for (int r = 0; r < 4; r++)
                    #pragma unroll
                    for (int q = 0; q < 4; q++) acc[r][q] += xi[r].y * xj[q].y;
            }
        }
        #pragma unroll
        for (int r = 0; r < 4; r++)
            #pragma unroll
            for (int q = 0; q < 4; q++) {
                double d2 = x2i[r] + sx2j[tx + 16 * q] - 2.0 * acc[r][q];
                mx[r] = fmax(mx[r], d2);
                ins5(best[r], d2);
            }
    }
    for (int m = 1; m <= 8; m <<= 1) {
        #pragma unroll
        for (int r = 0; r < 4; r++) {
            double p[KNN];
            #pragma unroll
            for (int k = 0; k < KNN; k++) p[k] = __shfl_xor(best[r][k], m);
            mx[r] = fmax(mx[r], __shfl_xor(mx[r], m));
            merge5(best[r], p);
        }
    }
    if (tx == 0) {
        #pragma unroll
        for (int r = 0; r < 4; r++) {
            int gi = b * Nq + i0 + ty + 16 * r;
            size_t base = ((size_t)s * BNq + gi) * KNN;
            #pragma unroll
            for (int k = 0; k < KNN; k++) pbest[base + k] = best[r][k];
            pmax[(size_t)s * BNq + gi] = mx[r];
        }
    }
}

// merge pass1 partials -> density; fold per-batch max into maxd2 via atomic
// (f64 max is exact/commutative; values are positive -> PosD trick valid;
// maxd2 is in the zero-initialized workspace region).
__global__ void ctm_merge1(const double* __restrict__ pbest, const double* __restrict__ pmax,
                           double* density, double* maxd2) {
    int t = blockIdx.x * blockDim.x + threadIdx.x;
    if (t >= BNq) return;
    double a[KNN];
    #pragma unroll
    for (int k = 0; k < KNN; k++) a[k] = pbest[(size_t)t * KNN + k];
    double mxv = pmax[t];
    #pragma unroll
    for (int s = 1; s < NSPL; s++) {
        double p[KNN];
        #pragma unroll
        for (int k = 0; k < KNN; k++) p[k] = pbest[((size_t)s * BNq + t) * KNN + k];
        merge5(a, p);
        mxv = fmax(mxv, pmax[(size_t)s * BNq + t]);
    }
    double sum = 0.0;
    #pragma unroll
    for (int k = 0; k < KNN; k++) sum += fmax(a[k], 0.0);
    density[t] = exp(-sum / (double)(C2q * KNN)) + (double)(tf_uniform(t) * 1e-6f);
    atomicMaxPosD(&maxd2[t / Nq], mxv);
}

// pass2: min d2 over higher-density j (partial per j-split)
__global__ __launch_bounds__(256, 2)
void ctm_pass2(const double* __restrict__ xt, const double* __restrict__ x2,
               const double* __restrict__ density, double* pmin) {
    __shared__ double sA[T64][LDP];
    __shared__ double sB[T64][LDP];
    __shared__ double sx2j[T64];
    __shared__ double sdj[T64];
    int blk = blockIdx.x;
    int b  = blk & (Bq - 1);
    int s  = (blk >> 2) & (NSPL - 1);
    int it = blk >> 5;
    int tid = threadIdx.x, tx = tid & 15, ty = tid >> 4;
    const double* xtb = xt + (size_t)b * Nq * C2q;
    const double* x2b = x2 + (size_t)b * Nq;
    const double* db  = density + (size_t)b * Nq;
    int i0 = it * T64;
    double x2i[4], di[4], mn[4];
    #pragma unroll
    for (int r = 0; r < 4; r++) {
        x2i[r] = x2b[i0 + ty + 16 * r];
        di[r]  = db[i0 + ty + 16 * r];
        mn[r]  = DBL_MAX;
    }
    int jt_beg = c_spl[s], jt_end = c_spl[s + 1];
    for (int jt = jt_beg; jt < jt_end; jt++) {
        int j0 = jt * T64;
        double acc[4][4];
        #pragma unroll
        for (int r = 0; r < 4; r++)
            #pragma unroll
            for (int q = 0; q < 4; q++) acc[r][q] = 0.0;
        for (int kc = 0; kc < 4; kc++) {
            __syncthreads();
            for (int idx = tid; idx < T64 * KC; idx += 256) {
                int r = idx >> 5, c = idx & 31;
                sA[r][c] = xtb[(size_t)(i0 + r) * C2q + kc * KC + c];
                sB[r][c] = xtb[(size_t)(j0 + r) * C2q + kc * KC + c];
            }
            if (kc == 0 && tid < T64) { sx2j[tid] = x2b[j0 + tid]; sdj[tid] = db[j0 + tid]; }
            __syncthreads();
            #pragma unroll 4
            for (int cc = 0; cc < KC; cc += 2) {
                double2 xi[4], xj[4];
                #pragma unroll
                for (int r = 0; r < 4; r++) xi[r] = *(const double2*)&sA[ty + 16 * r][cc];
                #pragma unroll
                for (int q = 0; q < 4; q++) xj[q] = *(const double2*)&sB[tx + 16 * q][cc];
                #pragma unroll
                for (int r = 0; r < 4; r++)
                    #pragma unroll
                    for (int q = 0; q < 4; q++) acc[r][q] += xi[r].x * xj[q].x;
                #pragma unroll
                for (int r = 0; r < 4; r++)
                    #pragma unroll
                    for (int q = 0; q < 4; q++) acc[r][q] += xi[r].y * xj[q].y;
            }
        }
        #pragma unroll
        for (int r = 0; r < 4; r++)
            #pragma unroll
            for (int q = 0; q < 4; q++) {
                double d2 = x2i[r] + sx2j[tx + 16 * q] - 2.0 * acc[r][q];
                if (sdj[tx + 16 * q] > di[r]) mn[r] = fmin(mn[r], d2);
            }
    }
    for (int m = 1; m <= 8; m <<= 1) {
        #pragma unroll
        for (int r = 0; r < 4; r++) mn[r] = fmin(mn[r], __shfl_xor(mn[r], m));
    }
    if (tx == 0) {
        #pragma unroll
        for (int r = 0; r < 4; r++) {
            int gi = b * Nq + i0 + ty + 16 * r;
            pmin[(size_t)s * BNq + gi] = mn[r];
        }
    }
}

// merge pass2 partials -> score
__global__ void ctm_merge2(const double* __restrict__ pmin, const double* __restrict__ maxd2,
                           const double* __restrict__ density, double* score) {
    int t = blockIdx.x * blockDim.x + threadIdx.x;
    if (t >= BNq) return;
    int b = t / Nq;
    double m = pmin[t];
    #pragma unroll
    for (int s = 1; s < NSPL; s++) m = fmin(m, pmin[(size_t)s * BNq + t]);
    double mm = fmin(maxd2[b], m);
    score[t] = sqrt(fmax(mm, 0.0)) / sqrt((double)C2q) * density[t];
}

// top-784 with jax.lax.top_k semantics: total order (score desc, idx asc).
__global__ __launch_bounds__(1024)
void ctm_sort(const double* __restrict__ score, int* index_down) {
    __shared__ double s[4096];
    __shared__ int   si[4096];
    int b = blockIdx.x, tid = threadIdx.x;
    for (int i = tid; i < 4096; i += 1024) {
        if (i < Nq) {
            double v = score[b * Nq + i];
            s[i] = isnan(v) ? -DBL_MAX : v;
            si[i] = i;
        } else { s[i] = -DBL_MAX; si[i] = 0x7fffffff; }
    }
    __syncthreads();
    for (int k = 2; k <= 4096; k <<= 1) {
        for (int j = k >> 1; j > 0; j >>= 1) {
            for (int i = tid; i < 4096; i += 1024) {
                int ixj = i ^ j;
                if (ixj > i) {
                    double s1 = s[i], s2 = s[ixj];
                    int i1 = si[i], i2 = si[ixj];
                    bool before_ij = (s1 > s2) || (s1 == s2 && i1 < i2);
                    bool before_ji = (s2 > s1) || (s2 == s1 && i2 < i1);
                    bool doswap = ((i & k) == 0) ? before_ji : before_ij;
                    if (doswap) { s[i] = s2; s[ixj] = s1; si[i] = i2; si[ixj] = i1; }
                }
            }
            __syncthreads();
        }
    }
    for (int t = tid; t < NSq; t += 1024) {
        int v = si[t];
        index_down[b * NSq + t] = ((unsigned)v < (unsigned)Nq) ? v : 0;
    }
}

// assign: argmin over centers (lexicographic (d,sc) min), split over center
// tiles x2 (R15 assign was grid-starved: 196 blocks = 0.77/CU).
__global__ __launch_bounds__(256, 2)
void ctm_assign(const double* __restrict__ xt, const double* __restrict__ x2,
                const int* __restrict__ index_down, double* pbd, int* pbs) {
    __shared__ double sA[T64][LDP];
    __shared__ double sB[T64][LDP];
    __shared__ double sx2c[T64];
    __shared__ int    sidx[T64];
    int blk = blockIdx.x;
    int b  = blk & (Bq - 1);
    int s  = (blk >> 2) & (NSPA - 1);
    int it = blk >> 3;
    int tid = threadIdx.x, tx = tid & 15, ty = tid >> 4;
    const double* xtb = xt + (size_t)b * Nq * C2q;
    const double* x2b = x2 + (size_t)b * Nq;
    int i0 = it * T64;
    double x2i[4], bd[4];
    int bs[4];
    #pragma unroll
    for (int r = 0; r < 4; r++) { x2i[r] = x2b[i0 + ty + 16 * r]; bd[r] = DBL_MAX; bs[r] = NSq - 1; }
    int jt_beg = c_spla[s], jt_end = c_spla[s + 1];
    for (int jt = jt_beg; jt < jt_end; jt++) {
        int j0 = jt * T64;
        __syncthreads();
        if (tid < T64) {
            int j = index_down[b * NSq + min(j0 + tid, NSq - 1)];
            sidx[tid] = j;
            sx2c[tid] = x2b[j];
        }
        __syncthreads();
        double acc[4][4];
        #pragma unroll
        for (int r = 0; r < 4; r++)
            #pragma unroll
            for (int q = 0; q < 4; q++) acc[r][q] = 0.0;
        for (int kc = 0; kc < 4; kc++) {
            if (kc) __syncthreads();
            for (int idx = tid; idx < T64 * KC; idx += 256) {
                int r = idx >> 5, c = idx & 31;
                sA[r][c] = xtb[(size_t)(i0 + r) * C2q + kc * KC + c];
                sB[r][c] = xtb[(size_t)sidx[r] * C2q + kc * KC + c];
            }
            __syncthreads();
            #pragma unroll 4
            for (int cc = 0; cc < KC; cc += 2) {
                double2 xi[4], xj[4];
                #pragma unroll
                for (int r = 0; r < 4; r++) xi[r] = *(const double2*)&sA[ty + 16 * r][cc];
                #pragma unroll
                for (int q = 0; q < 4; q++) xj[q] = *(const double2*)&sB[tx + 16 * q][cc];
                #pragma unroll
                for (int r = 0; r < 4; r++)
                    #pragma unroll
                    for (int q = 0; q < 4; q++) acc[r][q] += xi[r].x * xj[q].x;
                #pragma unroll
                for (int r = 0; r < 4; r++)
                    #pragma unroll
                    for (int q = 0; q < 4; q++) acc[r][q] += xi[r].y * xj[q].y;
            }
        }
        #pragma unroll
        for (int r = 0; r < 4; r++)
            #pragma unroll
            for (int q = 0; q < 4; q++) {
                int sc = j0 + tx + 16 * q;
                double d = fmax(x2i[r] + sx2c[tx + 16 * q] - 2.0 * acc[r][q], 0.0);
                if (sc < NSq && (d < bd[r] || (d == bd[r] && sc < bs[r]))) { bd[r] = d; bs[r] = sc; }
            }
    }
    for (int m = 1; m <= 8; m <<= 1) {
        #pragma unroll
        for (int r = 0; r < 4; r++) {
            double pd = __shfl_xor(bd[r], m);
            int    ps = __shfl_xor(bs[r], m);
            if (pd < bd[r] || (pd == bd[r] && ps < bs[r])) { bd[r] = pd; bs[r] = ps; }
        }
    }
    if (tx == 0) {
        #pragma unroll
        for (int r = 0; r < 4; r++) {
            int gi = b * Nq + i0 + ty + 16 * r;
            pbd[(size_t)s * BNq + gi] = bd[r];
            pbs[(size_t)s * BNq + gi] = bs[r];
        }
    }
}

// merge assign partials (lexicographic (d,sc) min == first-min semantics)
__global__ void ctm_merge3(const double* __restrict__ pbd, const int* __restrict__ pbs,
                           int* idx_cluster) {
    int t = blockIdx.x * blockDim.x + threadIdx.x;
    if (t >= BNq) return;
    double d0 = pbd[t];          int s0 = pbs[t];
    double d1 = pbd[BNq + t];    int s1 = pbs[BNq + t];
    bool take1 = (d1 < d0) || (d1 == d0 && s1 < s0);
    idx_cluster[t] = take1 ? s1 : s0;
}

__global__ void ctm_override(const int* __restrict__ index_down, int* idx_cluster) {
    int t = blockIdx.x * blockDim.x + threadIdx.x;
    if (t >= Bq * NSq) return;
    int b = t / NSq, sc = t - b * NSq;
    int j = index_down[t];
    if ((unsigned)j < (unsigned)Nq) idx_cluster[b * Nq + j] = sc;
}

__global__ void ctm_zeromerged(double* xmerged) {
    int t = blockIdx.x * blockDim.x + threadIdx.x;
    if (t < Bq * NSq * C2q) xmerged[t] = 0.0;
}

__global__ void ctm_merge_w(const int* __restrict__ idx_cluster, const double* __restrict__ weightv,
                            double* allwc) {
    int t = blockIdx.x * blockDim.x + threadIdx.x;
    if (t >= BNq) return;
    int b = t / Nq;
    int sc = min(max(idx_cluster[t], 0), NSq - 1);
    atomicAdd(&allwc[b * NSq + sc], weightv[t]);
}

// merge_x, (point,channel)-parallel: one coalesced atomic per thread.
__global__ void ctm_merge_x(const int* __restrict__ idx_cluster, const double* __restrict__ weightv,
                            const double* __restrict__ allwc, const double* __restrict__ xt,
                            double* nw, double* xmerged) {
    int id = blockIdx.x * blockDim.x + threadIdx.x;
    if (id >= BNq * C2q) return;
    int t = id / C2q, c = id - t * C2q;
    int b = t / Nq;
    int sc = min(max(idx_cluster[t], 0), NSq - 1);
    double nv = weightv[t] / (allwc[b * NSq + sc] + 1e-6);
    if (c == 0) nw[t] = nv;
    atomicAdd(&xmerged[((size_t)(b * NSq + sc)) * C2q + c], xt[(size_t)t * C2q + c] * nv);
}

__global__ void ctm_out0(const double* __restrict__ xmerged, float* out) {
    int t = blockIdx.x * blockDim.x + threadIdx.x;
    if (t >= Bq * NSq * C2q) return;
    out[t] = (float)xmerged[t];
}

__global__ void ctm_out12(const int* __restrict__ idx_agg, const int* __restrict__ idx_cluster,
                          const double* __restrict__ nw, const float* __restrict__ aggw,
                          float* out1, double* awd, double* maxawd) {
    int t = blockIdx.x * blockDim.x + threadIdx.x;
    if (t >= BNq) return;
    int b = t / Nq;
    int tok = clampTok(idx_agg[t]);
    int sc = idx_cluster[b * Nq + tok];
    out1[t] = (float)sc;
    double a = (double)aggw[t] * nw[b * Nq + tok];
    awd[t] = a;
    atomicMaxPosD(&maxawd[b], a);
}

__global__ void ctm_out2(const double* __restrict__ awd, const double* __restrict__ maxawd, float* out2) {
    int t = blockIdx.x * blockDim.x + threadIdx.x;
    if (t >= BNq) return;
    int b = t / Nq;
    out2[t] = (float)(awd[t] / maxawd[b]);
}

// ---------------------------------------------------------------------------
extern "C" void kernel_launch(void* const* d_in, const int* in_sizes, int n_in,
                              void* d_out, int out_size, void* d_ws, size_t ws_size,
                              hipStream_t stream) {
    const float* x     = (const float*)d_in[0];
    const float* loc   = (const float*)d_in[1];
    const int*   idxag = (const int*)  d_in[2];
    const float* aggw  = (const float*)d_in[3];
    const float* convw = (const float*)d_in[4];
    const float* convb = (const float*)d_in[5];
    const float* skipw = (const float*)d_in[6];
    const float* lng   = (const float*)d_in[7];
    const float* lnb   = (const float*)d_in[8];
    const float* confw = (const float*)d_in[9];
    const float* confb = (const float*)d_in[10];
    (void)in_sizes; (void)n_in;

    char* w = (char*)d_ws;
    size_t off = 0;
    auto alloc = [&](size_t bytes) -> void* {
        void* p = w + off; off = (off + bytes + 255) & ~(size_t)255; return p;
    };

    // ---- zero-initialized region (one memset) ----
    int*    cnt56   = (int*)   alloc((size_t)BNq * 4);
    double* allwtok = (double*)alloc((size_t)BNq * 8);
    double* xt      = (double*)alloc((size_t)BNq * C2q * 8);
    double* arena   = (double*)alloc((size_t)Bq * HWq * Cq * 8);   // xmap56T, later xmerged
    double* allwc   = (double*)alloc((size_t)Bq * NSq * 8);
    double* maxawd  = (double*)alloc((size_t)Bq * 8);
    double* maxd2   = (double*)alloc((size_t)Bq * 8);              // atomic max (init 0)
    size_t zero_bytes = off;
    // ---- non-zero region ----
    int*    cell56   = (int*)   alloc((size_t)BNq * 4);
    int*    cell28   = (int*)   alloc((size_t)BNq * 4);
    double* xmap28T  = (double*)alloc((size_t)Bq * HWOq * C2q * 8);
    float*  wT       = (float*) alloc((size_t)C2q * Cq * 9 * 4);
    double* x2       = (double*)alloc((size_t)BNq * 8);
    double* density  = (double*)alloc((size_t)BNq * 8);
    double* score    = (double*)alloc((size_t)BNq * 8);
    int*    indexdn  = (int*)   alloc((size_t)Bq * NSq * 4);
    int*    idxclu   = (int*)   alloc((size_t)BNq * 4);
    double* nw       = (double*)alloc((size_t)BNq * 8);
    double* weightv  = (double*)alloc((size_t)BNq * 8);
    double* awd      = (double*)alloc((size_t)BNq * 8);
    double* pbest    = (double*)alloc((size_t)NSPL * BNq * KNN * 8);
    double* pmax     = (double*)alloc((size_t)NSPL * BNq * 8);
    double* pmin     = (double*)alloc((size_t)NSPL * BNq * 8);
    double* pbd      = (double*)alloc((size_t)NSPA * BNq * 8);
    int*    pbs      = (int*)   alloc((size_t)NSPA * BNq * 4);
    size_t required = off;

    const int tb = 256;
    float* out = (float*)d_out;

    if (ws_size < required) {
        ctm_fallback<<<(out_size + tb - 1) / tb, tb, 0, stream>>>(out, out_size);
        return;
    }

    double* xmap56T = arena;
    double* xmerged = arena;   // reused after conv; re-zeroed below

    hipMemsetAsync(d_ws, 0, zero_bytes, stream);

    ctm_prep<<<(BNq + tb - 1) / tb, tb, 0, stream>>>(loc, idxag, aggw, cell56, cell28, cnt56, allwtok);
    ctm_wt<<<((C2q * Cq * 9) + tb - 1) / tb, tb, 0, stream>>>(convw, wT);
    ctm_t2m<<<((BNq * Cq) + tb - 1) / tb, tb, 0, stream>>>(x, idxag, cell56, cnt56, xmap56T);
    ctm_conv<<<Bq * (HWOq / 2), 256, 0, stream>>>(xmap56T, wT, convb, xmap28T);
    ctm_m2t<<<((BNq * C2q) + tb - 1) / tb, tb, 0, stream>>>(xmap28T, aggw, idxag, cell28, allwtok, xt);
    ctm_finalize<<<BNq, C2q, 0, stream>>>(xt, x, skipw, lng, lnb, confw, confb, x2, weightv);
    ctm_pass1<<<Bq * NSPL * NIT64, 256, 0, stream>>>(xt, x2, pbest, pmax);
    ctm_merge1<<<(BNq + tb - 1) / tb, tb, 0, stream>>>(pbest, pmax, density, maxd2);
    ctm_pass2<<<Bq * NSPL * NIT64, 256, 0, stream>>>(xt, x2, density, pmin);
    ctm_merge2<<<(BNq + tb - 1) / tb, tb, 0, stream>>>(pmin, maxd2, density, score);
    ctm_sort<<<Bq, 1024, 0, stream>>>(score, indexdn);
    ctm_assign<<<Bq * NSPA * NIT64, 256, 0, stream>>>(xt, x2, indexdn, pbd, pbs);
    ctm_merge3<<<(BNq + tb - 1) / tb, tb, 0, stream>>>(pbd, pbs, idxclu);
    ctm_override<<<((Bq * NSq) + tb - 1) / tb, tb, 0, stream>>>(indexdn, idxclu);
    ctm_zeromerged<<<((Bq * NSq * C2q) + tb - 1) / tb, tb, 0, stream>>>(xmerged);
    ctm_merge_w<<<(BNq + tb - 1) / tb, tb, 0, stream>>>(idxclu, weightv, allwc);
    ctm_merge_x<<<((BNq * C2q) + tb - 1) / tb, tb, 0, stream>>>(idxclu, weightv, allwc, xt, nw, xmerged);

    ctm_out0<<<((Bq * NSq * C2q) + tb - 1) / tb, tb, 0, stream>>>(xmerged, out);
    ctm_out12<<<(BNq + tb - 1) / tb, tb, 0, stream>>>(idxag, idxclu, nw, aggw,
                                                      out + (size_t)Bq * NSq * C2q, awd, maxawd);
    ctm_out2<<<(BNq + tb - 1) / tb, tb, 0, stream>>>(awd, maxawd,
                                                     out + (size_t)Bq * NSq * C2q + BNq);
}

// Round 17
// 1466.414 us; speedup vs baseline: 1.4096x; 1.0117x over previous
//
#include <hip/hip_runtime.h>
#include <math.h>
#include <float.h>

// Problem constants: B=4, N=3136, C=64, C2=128, H=W=56, stride2 -> 28x28,
// Ns = ceil(N*0.25) = 784, k = 5.  Inputs are float32/int32 per reference.
#define Bq   4
#define Nq   3136
#define Cq   64
#define C2q  128
#define Hq   56
#define Wq   56
#define HWq  (Hq*Wq)
#define HOq  28
#define WOq  28
#define HWOq (HOq*WOq)
#define NSq  784
#define KNN  5
#define BNq  (Bq*Nq)

#define T64   64             // i/j tile for distance kernels
#define KC    32             // K chunk
#define NIT64 (Nq/T64)       // 49 i-tiles (exact)
#define NT_C  ((NSq+T64-1)/T64) // 13 center tiles (last partial)
#define NSPL  8              // j-range splits (grid 1568)
#define NSPA  2              // assign center-range splits
#define LDP   34             // LDS row stride (even -> 16B-aligned double2)

__device__ __constant__ int c_spl[NSPL + 1]  = {0, 7, 13, 19, 25, 31, 37, 43, 49};
__device__ __constant__ int c_spla[NSPA + 1] = {0, 7, 13};

typedef unsigned int   u32;
typedef unsigned long long u64;

static __device__ __forceinline__ void atomicMaxPosD(double* p, double v) {
    // valid for non-negative doubles: bit pattern is order-isomorphic
    atomicMax((u64*)p, (u64)__double_as_longlong(v));
}
static __device__ __forceinline__ int clampTok(int t) {
    return min(max(t, 0), Nq - 1);
}

// sorted-ascending insert into 5-list (static indices after unroll)
static __device__ __forceinline__ void ins5(double* a, double v) {
    if (v < a[KNN - 1]) {
        a[KNN - 1] = v;
        #pragma unroll
        for (int m = KNN - 1; m > 0; m--)
            if (a[m] < a[m - 1]) { double t = a[m]; a[m] = a[m - 1]; a[m - 1] = t; }
    }
}
// compare-exchange (branch-free, static)
static __device__ __forceinline__ void cex(double& a, double& b) {
    double lo = fmin(a, b), hi = fmax(a, b); a = lo; b = hi;
}
// merge two ascending 5-lists, keep 5 smallest ascending.
// STATIC INDICES ONLY (SROA -> VGPRs; dynamic idx caused 338 MB spill, R7/R8).
static __device__ __forceinline__ void merge5(double* a, const double* p) {
    double t0 = fmin(a[0], p[4]);
    double t1 = fmin(a[1], p[3]);
    double t2 = fmin(a[2], p[2]);
    double t3 = fmin(a[3], p[1]);
    double t4 = fmin(a[4], p[0]);
    cex(t0, t1); cex(t1, t2); cex(t2, t3); cex(t3, t4);
    cex(t0, t1); cex(t1, t2); cex(t2, t3);
    cex(t0, t1); cex(t1, t2);
    cex(t0, t1);
    a[0] = t0; a[1] = t1; a[2] = t2; a[3] = t3; a[4] = t4;
}

// ---- jax threefry2x32 noise: uniform(key(42), (4,3136)) -------------------
static __device__ __forceinline__ u32 rotl32(u32 x, int d) { return (x << d) | (x >> (32 - d)); }
static __device__ __forceinline__ float tf_uniform(int t) {
    const u32 k0 = 0u, k1 = 42u;
    const u32 ks2 = k0 ^ k1 ^ 0x1BD11BDAu;
    u32 ks[3] = { k0, k1, ks2 };
    bool lo = (t < 6272);
    u32 cx0 = lo ? (u32)t : (u32)(t - 6272);
    u32 cx1 = lo ? (u32)(t + 6272) : (u32)t;
    u32 x0 = cx0 + ks[0];
    u32 x1 = cx1 + ks[1];
    const int R0[4] = {13, 15, 26, 6};
    const int R1[4] = {17, 29, 16, 24};
    #pragma unroll
    for (int i = 0; i < 5; i++) {
        const int* rot = (i % 2 == 0) ? R0 : R1;
        #pragma unroll
        for (int r = 0; r < 4; r++) { x0 += x1; x1 = rotl32(x1, rot[r]); x1 ^= x0; }
        x0 += ks[(i + 1) % 3];
        x1 += ks[(i + 2) % 3] + (u32)(i + 1);
    }
    u32 bits = lo ? x0 : x1;
    u32 fb = (bits >> 9) | 0x3f800000u;
    float f; __builtin_memcpy(&f, &fb, 4);
    return f - 1.0f;
}

// ---- grid index: clip(loc,-1,1)*0.5+0.5 -> round-half-even ----------------
static __device__ __forceinline__ int gridIndex(float lx, float ly, int Wd, int Hd) {
    double x = fmin(fmax((double)lx, -1.0), 1.0) * 0.5 + 0.5;
    double y = fmin(fmax((double)ly, -1.0), 1.0) * 0.5 + 0.5;
    int ix = (int)rint(x * (double)(Wd - 1)); ix = min(max(ix, 0), Wd - 1);
    int iy = (int)rint(y * (double)(Hd - 1)); iy = min(max(iy, 0), Hd - 1);
    return iy * Wd + ix;
}

// ---------------------------------------------------------------------------
__global__ void ctm_fallback(float* out, int n) {
    int t = blockIdx.x * blockDim.x + threadIdx.x;
    if (t < n) out[t] = 0.0f;
}

__global__ void ctm_prep(const float* __restrict__ loc, const int* __restrict__ idx_agg,
                         const float* __restrict__ aggw,
                         int* cell56, int* cell28, int* cnt56, double* allwtok) {
    int t = blockIdx.x * blockDim.x + threadIdx.x;
    if (t >= BNq) return;
    int b = t / Nq;
    float lx = loc[2 * t], ly = loc[2 * t + 1];
    int c56 = gridIndex(lx, ly, Wq, Hq);
    int c28 = gridIndex(lx, ly, WOq, HOq);
    cell56[t] = c56; cell28[t] = c28;
    atomicAdd(&cnt56[b * HWq + c56], 1);
    int tok = clampTok(idx_agg[t]);
    atomicAdd(&allwtok[b * Nq + tok], (double)aggw[t]);
}

// t2m, (point,channel)-parallel: one coalesced f64 atomic per thread.
__global__ void ctm_t2m(const float* __restrict__ x, const int* __restrict__ idx_agg,
                        const int* __restrict__ cell56, const int* __restrict__ cnt56,
                        double* xmap56T) {
    int id = blockIdx.x * blockDim.x + threadIdx.x;
    if (id >= BNq * Cq) return;
    int t = id / Cq, c = id - t * Cq;
    int b = t / Nq;
    int cell = cell56[t];
    double v = 1.0 / ((double)cnt56[b * HWq + cell] + 1e-6);
    double xv = (double)x[(size_t)(b * Nq + clampTok(idx_agg[t])) * Cq + c];
    atomicAdd(&xmap56T[((size_t)b * HWq + cell) * Cq + c], xv * v);
}

// one-time weight transpose: wT[(ci*9+tap)*C2q+co] = w[co*Cq*9 + ci*9 + tap]
__global__ void ctm_wt(const float* __restrict__ w, float* wT) {
    int id = blockIdx.x * blockDim.x + threadIdx.x;
    if (id >= C2q * Cq * 9) return;
    int co = id & (C2q - 1);
    int rem = id >> 7;
    int tap = rem % 9;
    int ci = rem / 9;
    wT[id] = w[(size_t)co * Cq * 9 + ci * 9 + tap];
}

// conv 3x3 stride2: block = 2 cells x 128 co, input taps staged in LDS
// (OOB -> 0.0, bit-neutral), wT lane-coalesced.
__global__ __launch_bounds__(256)
void ctm_conv(const double* __restrict__ xmap56T, const float* __restrict__ wT,
              const float* __restrict__ bias, double* xmap28T) {
    __shared__ double sIn[2][9][Cq];
    int blk = blockIdx.x;
    int b  = blk & (Bq - 1);
    int cp = blk >> 2;              // cell pair index, 0..391
    int tid = threadIdx.x;
    int co = tid & (C2q - 1);
    int cl = tid >> 7;              // 0 or 1
    const double* xb = xmap56T + (size_t)b * HWq * Cq;
    for (int idx = tid; idx < 2 * 9 * Cq; idx += 256) {
        int cell_l = idx / (9 * Cq);
        int rem = idx - cell_l * (9 * Cq);
        int tap = rem >> 6;
        int ci  = rem & 63;
        int cell = 2 * cp + cell_l;
        int ox = cell % WOq, oy = cell / WOq;
        int ky = tap / 3, kx = tap - ky * 3;
        int iy = 2 * oy + ky - 1, ix = 2 * ox + kx - 1;
        double v = 0.0;
        if (iy >= 0 && iy < Hq && ix >= 0 && ix < Wq)
            v = xb[(size_t)(iy * Wq + ix) * Cq + ci];
        sIn[cell_l][tap][ci] = v;
    }
    __syncthreads();
    double acc = (double)bias[co];
    for (int ci = 0; ci < Cq; ci++) {
        #pragma unroll
        for (int tap = 0; tap < 9; tap++)
            acc += sIn[cl][tap][ci] * (double)wT[(size_t)(ci * 9 + tap) * C2q + co];
    }
    int cell = 2 * cp + cl;
    xmap28T[((size_t)b * HWOq + cell) * C2q + co] = acc;
}

// m2t, (point,channel)-parallel: coalesced.
__global__ void ctm_m2t(const double* __restrict__ xmap28T, const float* __restrict__ aggw,
                        const int* __restrict__ idx_agg, const int* __restrict__ cell28,
                        const double* __restrict__ allwtok, double* xt) {
    int id = blockIdx.x * blockDim.x + threadIdx.x;
    if (id >= BNq * C2q) return;
    int t = id / C2q, c = id - t * C2q;
    int b = t / Nq;
    int tok = clampTok(idx_agg[t]);
    double v = (double)aggw[t] / (allwtok[b * Nq + tok] + 1e-6);
    double f = xmap28T[((size_t)b * HWOq + cell28[t]) * C2q + c];
    atomicAdd(&xt[(size_t)(b * Nq + tok) * C2q + c], f * v);
}

__global__ __launch_bounds__(C2q)
void ctm_finalize(double* xt, const float* __restrict__ x, const float* __restrict__ skipw,
                  const float* __restrict__ lng, const float* __restrict__ lnb,
                  const float* __restrict__ confw, const float* __restrict__ confb,
                  double* x2o, double* weightv) {
    int bn = blockIdx.x; int c = threadIdx.x;
    double* row = xt + (size_t)bn * C2q;
    const float* xr = x + (size_t)bn * Cq;
    double acc = row[c];
    const float* sw = skipw + c * Cq;
    #pragma unroll 16
    for (int k = 0; k < Cq; k++) acc += (double)xr[k] * (double)sw[k];
    __shared__ double red[C2q];
    __shared__ double stat[2];
    red[c] = acc; __syncthreads();
    for (int off = C2q / 2; off > 0; off >>= 1) { if (c < off) red[c] += red[c + off]; __syncthreads(); }
    if (c == 0) stat[0] = red[0] * (1.0 / C2q);
    __syncthreads();
    double mu = stat[0];
    double d = acc - mu;
    red[c] = d * d; __syncthreads();
    for (int off = C2q / 2; off > 0; off >>= 1) { if (c < off) red[c] += red[c + off]; __syncthreads(); }
    if (c == 0) stat[1] = red[0] * (1.0 / C2q);
    __syncthreads();
    double var = stat[1];
    double v = d / sqrt(var + 1e-5) * (double)lng[c] + (double)lnb[c];
    row[c] = v;
    red[c] = v * v; __syncthreads();
    for (int off = C2q / 2; off > 0; off >>= 1) { if (c < off) red[c] += red[c + off]; __syncthreads(); }
    if (c == 0) x2o[bn] = red[0];
    __syncthreads();
    red[c] = v * (double)confw[c]; __syncthreads();
    for (int off = C2q / 2; off > 0; off >>= 1) { if (c < off) red[c] += red[c + off]; __syncthreads(); }
    if (c == 0) weightv[bn] = exp(red[0] + (double)confb[0]);
}

// ---------------------------------------------------------------------------
// Distance kernels v2.7: as R16 ((256,2) no-spill, XCD swizzle b-fastest,
// NSPL=8) with double2-vectorized staging: 4 iterations of 2x
// global_load_dwordx2 -> ds_write_b128 per chunk instead of 8 scalar pairs
// (halves staging instructions + address VALU; R16 VALUBusy 48% included
// substantial staging overhead). Alignment: xt rows 1KB-strided, LDP=34 keeps
// LDS rows 16B-aligned. Zero arithmetic change.
// ---------------------------------------------------------------------------

// pass1: per row i -> 5 smallest d2 + row max d2 (partial per j-split)
__global__ __launch_bounds__(256, 2)
void ctm_pass1(const double* __restrict__ xt, const double* __restrict__ x2,
               double* pbest, double* pmax) {
    __shared__ double sA[T64][LDP];
    __shared__ double sB[T64][LDP];
    __shared__ double sx2j[T64];
    int blk = blockIdx.x;
    int b  = blk & (Bq - 1);
    int s  = (blk >> 2) & (NSPL - 1);
    int it = blk >> 5;
    int tid = threadIdx.x, tx = tid & 15, ty = tid >> 4;
    const double* xtb = xt + (size_t)b * Nq * C2q;
    const double* x2b = x2 + (size_t)b * Nq;
    int i0 = it * T64;
    double x2i[4];
    #pragma unroll
    for (int r = 0; r < 4; r++) x2i[r] = x2b[i0 + ty + 16 * r];
    double best[4][KNN]; double mx[4];
    #pragma unroll
    for (int r = 0; r < 4; r++) {
        mx[r] = -DBL_MAX;
        #pragma unroll
        for (int k = 0; k < KNN; k++) best[r][k] = DBL_MAX;
    }
    int jt_beg = c_spl[s], jt_end = c_spl[s + 1];
    for (int jt = jt_beg; jt < jt_end; jt++) {
        int j0 = jt * T64;
        double acc[4][4];
        #pragma unroll
        for (int r = 0; r < 4; r++)
            #pragma unroll
            for (int q = 0; q < 4; q++) acc[r][q] = 0.0;
        for (int kc = 0; kc < 4; kc++) {
            __syncthreads();
            #pragma unroll
            for (int idx = tid; idx < T64 * KC / 2; idx += 256) {
                int r = idx >> 4, c = (idx & 15) * 2;
                *(double2*)&sA[r][c] = *(const double2*)&xtb[(size_t)(i0 + r) * C2q + kc * KC + c];
                *(double2*)&sB[r][c] = *(const double2*)&xtb[(size_t)(j0 + r) * C2q + kc * KC + c];
            }
            if (kc == 0 && tid < T64) sx2j[tid] = x2b[j0 + tid];
            __syncthreads();
            #pragma unroll 4
            for (int cc = 0; cc < KC; cc += 2) {
                double2 xi[4], xj[4];
                #pragma unroll
                for (int r = 0; r < 4; r++) xi[r] = *(const double2*)&sA[ty + 16 * r][cc];
                #pragma unroll
                for (int q = 0; q < 4; q++) xj[q] = *(const double2*)&sB[tx + 16 * q][cc];
                #pragma unroll
                for (int r = 0; r < 4; r++)
                    #pragma unroll
                    for (int q = 0; q < 4; q++) acc[r][q] += xi[r].x * xj[q].x;
                #pragma unroll
                for (int r = 0; r < 4; r++)
                    #pragma unroll
                    for (int q = 0; q < 4; q++) acc[r][q] += xi[r].y * xj[q].y;
            }
        }
        #pragma unroll
        for (int r = 0; r < 4; r++)
            #pragma unroll
            for (int q = 0; q < 4; q++) {
                double d2 = x2i[r] + sx2j[tx + 16 * q] - 2.0 * acc[r][q];
                mx[r] = fmax(mx[r], d2);
                ins5(best[r], d2);
            }
    }
    for (int m = 1; m <= 8; m <<= 1) {
        #pragma unroll
        for (int r = 0; r < 4; r++) {
            double p[KNN];
            #pragma unroll
            for (int k = 0; k < KNN; k++) p[k] = __shfl_xor(best[r][k], m);
            mx[r] = fmax(mx[r], __shfl_xor(mx[r], m));
            merge5(best[r], p);
        }
    }
    if (tx == 0) {
        #pragma unroll
        for (int r = 0; r < 4; r++) {
            int gi = b * Nq + i0 + ty + 16 * r;
            size_t base = ((size_t)s * BNq + gi) * KNN;
            #pragma unroll
            for (int k = 0; k < KNN; k++) pbest[base + k] = best[r][k];
            pmax[(size_t)s * BNq + gi] = mx[r];
        }
    }
}

// merge pass1 partials -> density; fold per-batch max into maxd2 via atomic.
__global__ void ctm_merge1(const double* __restrict__ pbest, const double* __restrict__ pmax,
                           double* density, double* maxd2) {
    int t = blockIdx.x * blockDim.x + threadIdx.x;
    if (t >= BNq) return;
    double a[KNN];
    #pragma unroll
    for (int k = 0; k < KNN; k++) a[k] = pbest[(size_t)t * KNN + k];
    double mxv = pmax[t];
    #pragma unroll
    for (int s = 1; s < NSPL; s++) {
        double p[KNN];
        #pragma unroll
        for (int k = 0; k < KNN; k++) p[k] = pbest[((size_t)s * BNq + t) * KNN + k];
        merge5(a, p);
        mxv = fmax(mxv, pmax[(size_t)s * BNq + t]);
    }
    double sum = 0.0;
    #pragma unroll
    for (int k = 0; k < KNN; k++) sum += fmax(a[k], 0.0);
    density[t] = exp(-sum / (double)(C2q * KNN)) + (double)(tf_uniform(t) * 1e-6f);
    atomicMaxPosD(&maxd2[t / Nq], mxv);
}

// pass2: min d2 over higher-density j (partial per j-split)
__global__ __launch_bounds__(256, 2)
void ctm_pass2(const double* __restrict__ xt, const double* __restrict__ x2,
               const double* __restrict__ density, double* pmin) {
    __shared__ double sA[T64][LDP];
    __shared__ double sB[T64][LDP];
    __shared__ double sx2j[T64];
    __shared__ double sdj[T64];
    int blk = blockIdx.x;
    int b  = blk & (Bq - 1);
    int s  = (blk >> 2) & (NSPL - 1);
    int it = blk >> 5;
    int tid = threadIdx.x, tx = tid & 15, ty = tid >> 4;
    const double* xtb = xt + (size_t)b * Nq * C2q;
    const double* x2b = x2 + (size_t)b * Nq;
    const double* db  = density + (size_t)b * Nq;
    int i0 = it * T64;
    double x2i[4], di[4], mn[4];
    #pragma unroll
    for (int r = 0; r < 4; r++) {
        x2i[r] = x2b[i0 + ty + 16 * r];
        di[r]  = db[i0 + ty + 16 * r];
        mn[r]  = DBL_MAX;
    }
    int jt_beg = c_spl[s], jt_end = c_spl[s + 1];
    for (int jt = jt_beg; jt < jt_end; jt++) {
        int j0 = jt * T64;
        double acc[4][4];
        #pragma unroll
        for (int r = 0; r < 4; r++)
            #pragma unroll
            for (int q = 0; q < 4; q++) acc[r][q] = 0.0;
        for (int kc = 0; kc < 4; kc++) {
            __syncthreads();
            #pragma unroll
            for (int idx = tid; idx < T64 * KC / 2; idx += 256) {
                int r = idx >> 4, c = (idx & 15) * 2;
                *(double2*)&sA[r][c] = *(const double2*)&xtb[(size_t)(i0 + r) * C2q + kc * KC + c];
                *(double2*)&sB[r][c] = *(const double2*)&xtb[(size_t)(j0 + r) * C2q + kc * KC + c];
            }
            if (kc == 0 && tid < T64) { sx2j[tid] = x2b[j0 + tid]; sdj[tid] = db[j0 + tid]; }
            __syncthreads();
            #pragma unroll 4
            for (int cc = 0; cc < KC; cc += 2) {
                double2 xi[4], xj[4];
                #pragma unroll
                for (int r = 0; r < 4; r++) xi[r] = *(const double2*)&sA[ty + 16 * r][cc];
                #pragma unroll
                for (int q = 0; q < 4; q++) xj[q] = *(const double2*)&sB[tx + 16 * q][cc];
                #pragma unroll
                for (int r = 0; r < 4; r++)
                    #pragma unroll
                    for (int q = 0; q < 4; q++) acc[r][q] += xi[r].x * xj[q].x;
                #pragma unroll
                for (int r = 0; r < 4; r++)
                    #pragma unroll
                    for (int q = 0; q < 4; q++) acc[r][q] += xi[r].y * xj[q].y;
            }
        }
        #pragma unroll
        for (int r = 0; r < 4; r++)
            #pragma unroll
            for (int q = 0; q < 4; q++) {
                double d2 = x2i[r] + sx2j[tx + 16 * q] - 2.0 * acc[r][q];
                if (sdj[tx + 16 * q] > di[r]) mn[r] = fmin(mn[r], d2);
            }
    }
    for (int m = 1; m <= 8; m <<= 1) {
        #pragma unroll
        for (int r = 0; r < 4; r++) mn[r] = fmin(mn[r], __shfl_xor(mn[r], m));
    }
    if (tx == 0) {
        #pragma unroll
        for (int r = 0; r < 4; r++) {
            int gi = b * Nq + i0 + ty + 16 * r;
            pmin[(size_t)s * BNq + gi] = mn[r];
        }
    }
}

// merge pass2 partials -> score
__global__ void ctm_merge2(const double* __restrict__ pmin, const double* __restrict__ maxd2,
                           const double* __restrict__ density, double* score) {
    int t = blockIdx.x * blockDim.x + threadIdx.x;
    if (t >= BNq) return;
    int b = t / Nq;
    double m = pmin[t];
    #pragma unroll
    for (int s = 1; s < NSPL; s++) m = fmin(m, pmin[(size_t)s * BNq + t]);
    double mm = fmin(maxd2[b], m);
    score[t] = sqrt(fmax(mm, 0.0)) / sqrt((double)C2q) * density[t];
}

// top-784 with jax.lax.top_k semantics: total order (score desc, idx asc).
__global__ __launch_bounds__(1024)
void ctm_sort(const double* __restrict__ score, int* index_down) {
    __shared__ double s[4096];
    __shared__ int   si[4096];
    int b = blockIdx.x, tid = threadIdx.x;
    for (int i = tid; i < 4096; i += 1024) {
        if (i < Nq) {
            double v = score[b * Nq + i];
            s[i] = isnan(v) ? -DBL_MAX : v;
            si[i] = i;
        } else { s[i] = -DBL_MAX; si[i] = 0x7fffffff; }
    }
    __syncthreads();
    for (int k = 2; k <= 4096; k <<= 1) {
        for (int j = k >> 1; j > 0; j >>= 1) {
            for (int i = tid; i < 4096; i += 1024) {
                int ixj = i ^ j;
                if (ixj > i) {
                    double s1 = s[i], s2 = s[ixj];
                    int i1 = si[i], i2 = si[ixj];
                    bool before_ij = (s1 > s2) || (s1 == s2 && i1 < i2);
                    bool before_ji = (s2 > s1) || (s2 == s1 && i2 < i1);
                    bool doswap = ((i & k) == 0) ? before_ji : before_ij;
                    if (doswap) { s[i] = s2; s[ixj] = s1; si[i] = i2; si[ixj] = i1; }
                }
            }
            __syncthreads();
        }
    }
    for (int t = tid; t < NSq; t += 1024) {
        int v = si[t];
        index_down[b * NSq + t] = ((unsigned)v < (unsigned)Nq) ? v : 0;
    }
}

// assign: argmin over centers (lexicographic (d,sc) min), split x2.
__global__ __launch_bounds__(256, 2)
void ctm_assign(const double* __restrict__ xt, const double* __restrict__ x2,
                const int* __restrict__ index_down, double* pbd, int* pbs) {
    __shared__ double sA[T64][LDP];
    __shared__ double sB[T64][LDP];
    __shared__ double sx2c[T64];
    __shared__ int    sidx[T64];
    int blk = blockIdx.x;
    int b  = blk & (Bq - 1);
    int s  = (blk >> 2) & (NSPA - 1);
    int it = blk >> 3;
    int tid = threadIdx.x, tx = tid & 15, ty = tid >> 4;
    const double* xtb = xt + (size_t)b * Nq * C2q;
    const double* x2b = x2 + (size_t)b * Nq;
    int i0 = it * T64;
    double x2i[4], bd[4];
    int bs[4];
    #pragma unroll
    for (int r = 0; r < 4; r++) { x2i[r] = x2b[i0 + ty + 16 * r]; bd[r] = DBL_MAX; bs[r] = NSq - 1; }
    int jt_beg = c_spla[s], jt_end = c_spla[s + 1];
    for (int jt = jt_beg; jt < jt_end; jt++) {
        int j0 = jt * T64;
        __syncthreads();
        if (tid < T64) {
            int j = index_down[b * NSq + min(j0 + tid, NSq - 1)];
            sidx[tid] = j;
            sx2c[tid] = x2b[j];
        }
        __syncthreads();
        double acc[4][4];
        #pragma unroll
        for (int r = 0; r < 4; r++)
            #pragma unroll
            for (int q = 0; q < 4; q++) acc[r][q] = 0.0;
        for (int kc = 0; kc < 4; kc++) {
            if (kc) __syncthreads();
            #pragma unroll
            for (int idx = tid; idx < T64 * KC / 2; idx += 256) {
                int r = idx >> 4, c = (idx & 15) * 2;
                *(double2*)&sA[r][c] = *(const double2*)&xtb[(size_t)(i0 + r) * C2q + kc * KC + c];
                *(double2*)&sB[r][c] = *(const double2*)&xtb[(size_t)sidx[r] * C2q + kc * KC + c];
            }
            __syncthreads();
            #pragma unroll 4
            for (int cc = 0; cc < KC; cc += 2) {
                double2 xi[4], xj[4];
                #pragma unroll
                for (int r = 0; r < 4; r++) xi[r] = *(const double2*)&sA[ty + 16 * r][cc];
                #pragma unroll
                for (int q = 0; q < 4; q++) xj[q] = *(const double2*)&sB[tx + 16 * q][cc];
                #pragma unroll
                for (int r = 0; r < 4; r++)
                    #pragma unroll
                    for (int q = 0; q < 4; q++) acc[r][q] += xi[r].x * xj[q].x;
                #pragma unroll
                for (int r = 0; r < 4; r++)
                    #pragma unroll
                    for (int q = 0; q < 4; q++) acc[r][q] += xi[r].y * xj[q].y;
            }
        }
        #pragma unroll
        for (int r = 0; r < 4; r++)
            #pragma unroll
            for (int q = 0; q < 4; q++) {
                int sc = j0 + tx + 16 * q;
                double d = fmax(x2i[r] + sx2c[tx + 16 * q] - 2.0 * acc[r][q], 0.0);
                if (sc < NSq && (d < bd[r] || (d == bd[r] && sc < bs[r]))) { bd[r] = d; bs[r] = sc; }
            }
    }
    for (int m = 1; m <= 8; m <<= 1) {
        #pragma unroll
        for (int r = 0; r < 4; r++) {
            double pd = __shfl_xor(bd[r], m);
            int    ps = __shfl_xor(bs[r], m);
            if (pd < bd[r] || (pd == bd[r] && ps < bs[r])) { bd[r] = pd; bs[r] = ps; }
        }
    }
    if (tx == 0) {
        #pragma unroll
        for (int r = 0; r < 4; r++) {
            int gi = b * Nq + i0 + ty + 16 * r;
            pbd[(size_t)s * BNq + gi] = bd[r];
            pbs[(size_t)s * BNq + gi] = bs[r];
        }
    }
}

// merge assign partials (lexicographic (d,sc) min == first-min semantics)
__global__ void ctm_merge3(const double* __restrict__ pbd, const int* __restrict__ pbs,
                           int* idx_cluster) {
    int t = blockIdx.x * blockDim.x + threadIdx.x;
    if (t >= BNq) return;
    double d0 = pbd[t];          int s0 = pbs[t];
    double d1 = pbd[BNq + t];    int s1 = pbs[BNq + t];
    bool take1 = (d1 < d0) || (d1 == d0 && s1 < s0);
    idx_cluster[t] = take1 ? s1 : s0;
}

__global__ void ctm_override(const int* __restrict__ index_down, int* idx_cluster) {
    int t = blockIdx.x * blockDim.x + threadIdx.x;
    if (t >= Bq * NSq) return;
    int b = t / NSq, sc = t - b * NSq;
    int j = index_down[t];
    if ((unsigned)j < (unsigned)Nq) idx_cluster[b * Nq + j] = sc;
}

__global__ void ctm_zeromerged(double* xmerged) {
    int t = blockIdx.x * blockDim.x + threadIdx.x;
    if (t < Bq * NSq * C2q) xmerged[t] = 0.0;
}

__global__ void ctm_merge_w(const int* __restrict__ idx_cluster, const double* __restrict__ weightv,
                            double* allwc) {
    int t = blockIdx.x * blockDim.x + threadIdx.x;
    if (t >= BNq) return;
    int b = t / Nq;
    int sc = min(max(idx_cluster[t], 0), NSq - 1);
    atomicAdd(&allwc[b * NSq + sc], weightv[t]);
}

// merge_x, (point,channel)-parallel: one coalesced atomic per thread.
__global__ void ctm_merge_x(const int* __restrict__ idx_cluster, const double* __restrict__ weightv,
                            const double* __restrict__ allwc, const double* __restrict__ xt,
                            double* nw, double* xmerged) {
    int id = blockIdx.x * blockDim.x + threadIdx.x;
    if (id >= BNq * C2q) return;
    int t = id / C2q, c = id - t * C2q;
    int b = t / Nq;
    int sc = min(max(idx_cluster[t], 0), NSq - 1);
    double nv = weightv[t] / (allwc[b * NSq + sc] + 1e-6);
    if (c == 0) nw[t] = nv;
    atomicAdd(&xmerged[((size_t)(b * NSq + sc)) * C2q + c], xt[(size_t)t * C2q + c] * nv);
}

__global__ void ctm_out0(const double* __restrict__ xmerged, float* out) {
    int t = blockIdx.x * blockDim.x + threadIdx.x;
    if (t >= Bq * NSq * C2q) return;
    out[t] = (float)xmerged[t];
}

__global__ void ctm_out12(const int* __restrict__ idx_agg, const int* __restrict__ idx_cluster,
                          const double* __restrict__ nw, const float* __restrict__ aggw,
                          float* out1, double* awd, double* maxawd) {
    int t = blockIdx.x * blockDim.x + threadIdx.x;
    if (t >= BNq) return;
    int b = t / Nq;
    int tok = clampTok(idx_agg[t]);
    int sc = idx_cluster[b * Nq + tok];
    out1[t] = (float)sc;
    double a = (double)aggw[t] * nw[b * Nq + tok];
    awd[t] = a;
    atomicMaxPosD(&maxawd[b], a);
}

__global__ void ctm_out2(const double* __restrict__ awd, const double* __restrict__ maxawd, float* out2) {
    int t = blockIdx.x * blockDim.x + threadIdx.x;
    if (t >= BNq) return;
    int b = t / Nq;
    out2[t] = (float)(awd[t] / maxawd[b]);
}

// ---------------------------------------------------------------------------
extern "C" void kernel_launch(void* const* d_in, const int* in_sizes, int n_in,
                              void* d_out, int out_size, void* d_ws, size_t ws_size,
                              hipStream_t stream) {
    const float* x     = (const float*)d_in[0];
    const float* loc   = (const float*)d_in[1];
    const int*   idxag = (const int*)  d_in[2];
    const float* aggw  = (const float*)d_in[3];
    const float* convw = (const float*)d_in[4];
    const float* convb = (const float*)d_in[5];
    const float* skipw = (const float*)d_in[6];
    const float* lng   = (const float*)d_in[7];
    const float* lnb   = (const float*)d_in[8];
    const float* confw = (const float*)d_in[9];
    const float* confb = (const float*)d_in[10];
    (void)in_sizes; (void)n_in;

    char* w = (char*)d_ws;
    size_t off = 0;
    auto alloc = [&](size_t bytes) -> void* {
        void* p = w + off; off = (off + bytes + 255) & ~(size_t)255; return p;
    };

    // ---- zero-initialized region (one memset) ----
    int*    cnt56   = (int*)   alloc((size_t)BNq * 4);
    double* allwtok = (double*)alloc((size_t)BNq * 8);
    double* xt      = (double*)alloc((size_t)BNq * C2q * 8);
    double* arena   = (double*)alloc((size_t)Bq * HWq * Cq * 8);   // xmap56T, later xmerged
    double* allwc   = (double*)alloc((size_t)Bq * NSq * 8);
    double* maxawd  = (double*)alloc((size_t)Bq * 8);
    double* maxd2   = (double*)alloc((size_t)Bq * 8);              // atomic max (init 0)
    size_t zero_bytes = off;
    // ---- non-zero region ----
    int*    cell56   = (int*)   alloc((size_t)BNq * 4);
    int*    cell28   = (int*)   alloc((size_t)BNq * 4);
    double* xmap28T  = (double*)alloc((size_t)Bq * HWOq * C2q * 8);
    float*  wT       = (float*) alloc((size_t)C2q * Cq * 9 * 4);
    double* x2       = (double*)alloc((size_t)BNq * 8);
    double* density  = (double*)alloc((size_t)BNq * 8);
    double* score    = (double*)alloc((size_t)BNq * 8);
    int*    indexdn  = (int*)   alloc((size_t)Bq * NSq * 4);
    int*    idxclu   = (int*)   alloc((size_t)BNq * 4);
    double* nw       = (double*)alloc((size_t)BNq * 8);
    double* weightv  = (double*)alloc((size_t)BNq * 8);
    double* awd      = (double*)alloc((size_t)BNq * 8);
    double* pbest    = (double*)alloc((size_t)NSPL * BNq * KNN * 8);
    double* pmax     = (double*)alloc((size_t)NSPL * BNq * 8);
    double* pmin     = (double*)alloc((size_t)NSPL * BNq * 8);
    double* pbd      = (double*)alloc((size_t)NSPA * BNq * 8);
    int*    pbs      = (int*)   alloc((size_t)NSPA * BNq * 4);
    size_t required = off;

    const int tb = 256;
    float* out = (float*)d_out;

    if (ws_size < required) {
        ctm_fallback<<<(out_size + tb - 1) / tb, tb, 0, stream>>>(out, out_size);
        return;
    }

    double* xmap56T = arena;
    double* xmerged = arena;   // reused after conv; re-zeroed below

    hipMemsetAsync(d_ws, 0, zero_bytes, stream);

    ctm_prep<<<(BNq + tb - 1) / tb, tb, 0, stream>>>(loc, idxag, aggw, cell56, cell28, cnt56, allwtok);
    ctm_wt<<<((C2q * Cq * 9) + tb - 1) / tb, tb, 0, stream>>>(convw, wT);
    ctm_t2m<<<((BNq * Cq) + tb - 1) / tb, tb, 0, stream>>>(x, idxag, cell56, cnt56, xmap56T);
    ctm_conv<<<Bq * (HWOq / 2), 256, 0, stream>>>(xmap56T, wT, convb, xmap28T);
    ctm_m2t<<<((BNq * C2q) + tb - 1) / tb, tb, 0, stream>>>(xmap28T, aggw, idxag, cell28, allwtok, xt);
    ctm_finalize<<<BNq, C2q, 0, stream>>>(xt, x, skipw, lng, lnb, confw, confb, x2, weightv);
    ctm_pass1<<<Bq * NSPL * NIT64, 256, 0, stream>>>(xt, x2, pbest, pmax);
    ctm_merge1<<<(BNq + tb - 1) / tb, tb, 0, stream>>>(pbest, pmax, density, maxd2);
    ctm_pass2<<<Bq * NSPL * NIT64, 256, 0, stream>>>(xt, x2, density, pmin);
    ctm_merge2<<<(BNq + tb - 1) / tb, tb, 0, stream>>>(pmin, maxd2, density, score);
    ctm_sort<<<Bq, 1024, 0, stream>>>(score, indexdn);
    ctm_assign<<<Bq * NSPA * NIT64, 256, 0, stream>>>(xt, x2, indexdn, pbd, pbs);
    ctm_merge3<<<(BNq + tb - 1) / tb, tb, 0, stream>>>(pbd, pbs, idxclu);
    ctm_override<<<((Bq * NSq) + tb - 1) / tb, tb, 0, stream>>>(indexdn, idxclu);
    ctm_zeromerged<<<((Bq * NSq * C2q) + tb - 1) / tb, tb, 0, stream>>>(xmerged);
    ctm_merge_w<<<(BNq + tb - 1) / tb, tb, 0, stream>>>(idxclu, weightv, allwc);
    ctm_merge_x<<<((BNq * C2q) + tb - 1) / tb, tb, 0, stream>>>(idxclu, weightv, allwc, xt, nw, xmerged);

    ctm_out0<<<((Bq * NSq * C2q) + tb - 1) / tb, tb, 0, stream>>>(xmerged, out);
    ctm_out12<<<(BNq + tb - 1) / tb, tb, 0, stream>>>(idxag, idxclu, nw, aggw,
                                                      out + (size_t)Bq * NSq * C2q, awd, maxawd);
    ctm_out2<<<(BNq + tb - 1) / tb, tb, 0, stream>>>(awd, maxawd,
                                                     out + (size_t)Bq * NSq * C2q + BNq);
}